// Round 1
// baseline (1918.597 us; speedup 1.0000x reference)
//
#include <hip/hip_runtime.h>

#define NA 100000
#define NP 200000
#define NT 50000
#define DA 128
#define DP 128
#define DT 64
#define E_AP 400000
#define E_PA 400000
#define E_TP 300000
#define HD 64
#define NOUT 4
#define NEG 0.01f

// ---------------- weight folding (tiny, 1 block) ----------------
__global__ void fold_weights(const float* __restrict__ l1_ap_Wr, const float* __restrict__ l1_tp_Wr,
                             const float* __restrict__ l1_ap_bl, const float* __restrict__ l1_tp_bl,
                             const float* __restrict__ l2_Wl, const float* __restrict__ l2_bl,
                             const float* __restrict__ l2_Wr,
                             const float* __restrict__ lin_W, const float* __restrict__ lin_b,
                             float* __restrict__ Wrc, float* __restrict__ blc,
                             float* __restrict__ Wfl, float* __restrict__ Wfr, float* __restrict__ bf) {
  int t = threadIdx.x;
  for (int i = t; i < DP * HD; i += 256) Wrc[i] = l1_ap_Wr[i] + l1_tp_Wr[i];
  if (t < HD) blc[t] = l1_ap_bl[t] + l1_tp_bl[t];
  // Wfl = l2_Wl @ lin_W, Wfr = l2_Wr @ lin_W  (64x4 each); t covers all 256 entries
  {
    int k = t >> 2, c = t & 3;
    float s1 = 0.f, s2 = 0.f;
    for (int j = 0; j < HD; ++j) {
      float lw = lin_W[j * NOUT + c];
      s1 += l2_Wl[k * HD + j] * lw;
      s2 += l2_Wr[k * HD + j] * lw;
    }
    Wfl[t] = s1;
    Wfr[t] = s2;
  }
  if (t < NOUT) {
    float s = lin_b[t];
    for (int j = 0; j < HD; ++j) s += l2_bl[j] * lin_W[j * NOUT + t];
    bf[t] = s;
  }
}

// ---------------- degree counting + reciprocal ----------------
__global__ void count_kernel(const int* __restrict__ dst, int E, int* __restrict__ cnt) {
  int i = blockIdx.x * blockDim.x + threadIdx.x;
  if (i < E) atomicAdd(&cnt[dst[i]], 1);
}

__global__ void rinv_kernel(const int* __restrict__ cnt, float* __restrict__ rinv, int n) {
  int i = blockIdx.x * blockDim.x + threadIdx.x;
  if (i < n) rinv[i] = 1.0f / (float)max(cnt[i], 1);
}

// ---------------- dense transform: C[N x 64] = X[N x K] @ W[K x 64] (+bias) ----------------
template <int K, bool BIAS>
__global__ __launch_bounds__(256) void xform_kernel(const float* __restrict__ X,
                                                    const float* __restrict__ W,
                                                    const float* __restrict__ bias,
                                                    float* __restrict__ C, int N) {
  __shared__ float Wl[K * HD];
  for (int i = threadIdx.x; i < K * HD; i += 256) Wl[i] = W[i];
  __syncthreads();
  int r = blockIdx.x * 4 + (threadIdx.x >> 6);
  int c = threadIdx.x & 63;
  if (r >= N) return;
  const float* xr = X + (size_t)r * K;
  float acc = BIAS ? bias[c] : 0.0f;
#pragma unroll 4
  for (int k = 0; k < K; ++k) acc += xr[k] * Wl[k * HD + c];
  C[(size_t)r * HD + c] = acc;
}

// ---------------- edge scatter: T[dst] += Y[src] * rinv[dst], 64-wide ----------------
__global__ __launch_bounds__(256) void scatter_kernel(const float* __restrict__ Y,
                                                      const int* __restrict__ src,
                                                      const int* __restrict__ dst,
                                                      const float* __restrict__ rinv,
                                                      float* __restrict__ T, int E) {
  int e = blockIdx.x * 4 + (threadIdx.x >> 6);
  int lane = threadIdx.x & 63;
  if (e >= E) return;
  int s = src[e], d = dst[e];
  float w = rinv[d];
  atomicAdd(&T[(size_t)d * HD + lane], Y[(size_t)s * HD + lane] * w);
}

// ---------------- leaky relu, vectorized ----------------
__global__ void lrelu_kernel(float4* __restrict__ T, int n4) {
  int i = blockIdx.x * blockDim.x + threadIdx.x;
  if (i < n4) {
    float4 v = T[i];
    v.x = v.x > 0.f ? v.x : NEG * v.x;
    v.y = v.y > 0.f ? v.y : NEG * v.y;
    v.z = v.z > 0.f ? v.z : NEG * v.z;
    v.w = v.w > 0.f ? v.w : NEG * v.w;
    T[i] = v;
  }
}

// ---------------- head: C[N x 4] = X[N x 64] @ W[64 x 4] (+bias) ----------------
template <bool BIAS>
__global__ __launch_bounds__(256) void head_kernel(const float* __restrict__ X,
                                                   const float* __restrict__ W,
                                                   const float* __restrict__ b,
                                                   float* __restrict__ C, int N) {
  __shared__ float Wl[HD * NOUT];
  if (threadIdx.x < HD * NOUT) Wl[threadIdx.x] = W[threadIdx.x];
  __syncthreads();
  int r = blockIdx.x * 256 + threadIdx.x;
  if (r >= N) return;
  const float4* xr = (const float4*)(X + (size_t)r * HD);
  float a0 = 0.f, a1 = 0.f, a2 = 0.f, a3 = 0.f;
#pragma unroll
  for (int k4 = 0; k4 < HD / 4; ++k4) {
    float4 x = xr[k4];
    int base = k4 * 4 * NOUT;
    a0 += x.x * Wl[base + 0] + x.y * Wl[base + 4] + x.z * Wl[base + 8] + x.w * Wl[base + 12];
    a1 += x.x * Wl[base + 1] + x.y * Wl[base + 5] + x.z * Wl[base + 9] + x.w * Wl[base + 13];
    a2 += x.x * Wl[base + 2] + x.y * Wl[base + 6] + x.z * Wl[base + 10] + x.w * Wl[base + 14];
    a3 += x.x * Wl[base + 3] + x.y * Wl[base + 7] + x.z * Wl[base + 11] + x.w * Wl[base + 15];
  }
  if (BIAS) { a0 += b[0]; a1 += b[1]; a2 += b[2]; a3 += b[3]; }
  float4 o; o.x = a0; o.y = a1; o.z = a2; o.w = a3;
  *(float4*)(C + (size_t)r * NOUT) = o;
}

// ---------------- layer-2 scatter, 4-wide ----------------
__global__ void scatter4_kernel(const float* __restrict__ z,
                                const int* __restrict__ src,
                                const int* __restrict__ dst,
                                const float* __restrict__ rinv,
                                float* __restrict__ T, int E) {
  int e = blockIdx.x * blockDim.x + threadIdx.x;
  if (e >= E) return;
  int s = src[e], d = dst[e];
  float w = rinv[d];
  float4 zv = *(const float4*)(z + (size_t)s * NOUT);
  atomicAdd(&T[(size_t)d * NOUT + 0], zv.x * w);
  atomicAdd(&T[(size_t)d * NOUT + 1], zv.y * w);
  atomicAdd(&T[(size_t)d * NOUT + 2], zv.z * w);
  atomicAdd(&T[(size_t)d * NOUT + 3], zv.w * w);
}

extern "C" void kernel_launch(void* const* d_in, const int* in_sizes, int n_in,
                              void* d_out, int out_size, void* d_ws, size_t ws_size,
                              hipStream_t stream) {
  const float* x_author = (const float*)d_in[0];
  const float* x_paper  = (const float*)d_in[1];
  const float* x_term   = (const float*)d_in[2];
  const int* src_ap = (const int*)d_in[3];
  const int* dst_ap = (const int*)d_in[4];
  const int* src_pa = (const int*)d_in[5];
  const int* dst_pa = (const int*)d_in[6];
  const int* src_tp = (const int*)d_in[7];
  const int* dst_tp = (const int*)d_in[8];
  // d_in[9], d_in[10] (pt relation) pruned — never reaches author logits
  const float* l1_ap_Wl = (const float*)d_in[11];
  const float* l1_ap_bl = (const float*)d_in[12];
  const float* l1_ap_Wr = (const float*)d_in[13];
  // l2_ap (14-16) pruned
  const float* l1_pa_Wl = (const float*)d_in[17];
  const float* l1_pa_bl = (const float*)d_in[18];
  const float* l1_pa_Wr = (const float*)d_in[19];
  const float* l2_pa_Wl = (const float*)d_in[20];
  const float* l2_pa_bl = (const float*)d_in[21];
  const float* l2_pa_Wr = (const float*)d_in[22];
  const float* l1_tp_Wl = (const float*)d_in[23];
  const float* l1_tp_bl = (const float*)d_in[24];
  const float* l1_tp_Wr = (const float*)d_in[25];
  // l2_tp (26-28), l1_pt (29-31), l2_pt (32-34) pruned
  const float* lin_W = (const float*)d_in[35];
  const float* lin_b = (const float*)d_in[36];
  float* out = (float*)d_out;

  // workspace carve-up (~174 MB)
  float* ws = (float*)d_ws;
  float* ya = ws;  ws += (size_t)NA * HD;     // x_author @ l1_ap_Wl
  float* yp = ws;  ws += (size_t)NP * HD;     // x_paper  @ l1_pa_Wl
  float* yt = ws;  ws += (size_t)NT * HD;     // x_term   @ l1_tp_Wl
  float* P1 = ws;  ws += (size_t)NP * HD;     // paper hidden accumulator
  float* A1 = ws;  ws += (size_t)NA * HD;     // author hidden accumulator
  float* z  = ws;  ws += (size_t)NP * NOUT;   // p1 @ Wfl (folded head)
  float* rinv_ap = ws; ws += NP;
  float* rinv_tp = ws; ws += NP;
  float* rinv_pa = ws; ws += NA;
  int* cnt = (int*)ws; ws += (size_t)2 * NP + NA;  // 3 contiguous count arrays
  int* cnt_ap = cnt;
  int* cnt_tp = cnt + NP;
  int* cnt_pa = cnt + 2 * NP;
  float* Wrc = ws; ws += DP * HD;   // l1_ap_Wr + l1_tp_Wr
  float* blc = ws; ws += HD;        // l1_ap_bl + l1_tp_bl
  float* Wfl = ws; ws += HD * NOUT; // l2_pa_Wl @ lin_W
  float* Wfr = ws; ws += HD * NOUT; // l2_pa_Wr @ lin_W
  float* bf  = ws; ws += NOUT;      // l2_pa_bl @ lin_W + lin_b

  hipMemsetAsync(cnt, 0, ((size_t)2 * NP + NA) * sizeof(int), stream);
  fold_weights<<<1, 256, 0, stream>>>(l1_ap_Wr, l1_tp_Wr, l1_ap_bl, l1_tp_bl,
                                      l2_pa_Wl, l2_pa_bl, l2_pa_Wr, lin_W, lin_b,
                                      Wrc, blc, Wfl, Wfr, bf);

  count_kernel<<<(E_AP + 255) / 256, 256, 0, stream>>>(dst_ap, E_AP, cnt_ap);
  count_kernel<<<(E_TP + 255) / 256, 256, 0, stream>>>(dst_tp, E_TP, cnt_tp);
  count_kernel<<<(E_PA + 255) / 256, 256, 0, stream>>>(dst_pa, E_PA, cnt_pa);
  rinv_kernel<<<(NP + 255) / 256, 256, 0, stream>>>(cnt_ap, rinv_ap, NP);
  rinv_kernel<<<(NP + 255) / 256, 256, 0, stream>>>(cnt_tp, rinv_tp, NP);
  rinv_kernel<<<(NA + 255) / 256, 256, 0, stream>>>(cnt_pa, rinv_pa, NA);

  // feature transforms (project to H=64 BEFORE aggregation; root terms init accumulators)
  xform_kernel<128, false><<<(NA + 3) / 4, 256, 0, stream>>>(x_author, l1_ap_Wl, nullptr, ya, NA);
  xform_kernel<128, false><<<(NP + 3) / 4, 256, 0, stream>>>(x_paper, l1_pa_Wl, nullptr, yp, NP);
  xform_kernel<64,  false><<<(NT + 3) / 4, 256, 0, stream>>>(x_term, l1_tp_Wl, nullptr, yt, NT);
  xform_kernel<128, true ><<<(NP + 3) / 4, 256, 0, stream>>>(x_paper, Wrc, blc, P1, NP);
  xform_kernel<128, true ><<<(NA + 3) / 4, 256, 0, stream>>>(x_author, l1_pa_Wr, l1_pa_bl, A1, NA);

  // mean-aggregation fused into scatter via per-dst reciprocal counts
  scatter_kernel<<<(E_AP + 3) / 4, 256, 0, stream>>>(ya, src_ap, dst_ap, rinv_ap, P1, E_AP);
  scatter_kernel<<<(E_TP + 3) / 4, 256, 0, stream>>>(yt, src_tp, dst_tp, rinv_tp, P1, E_TP);
  scatter_kernel<<<(E_PA + 3) / 4, 256, 0, stream>>>(yp, src_pa, dst_pa, rinv_pa, A1, E_PA);

  lrelu_kernel<<<((NP * HD / 4) + 255) / 256, 256, 0, stream>>>((float4*)P1, NP * HD / 4);
  lrelu_kernel<<<((NA * HD / 4) + 255) / 256, 256, 0, stream>>>((float4*)A1, NA * HD / 4);

  // folded layer-2 + lin head: aggregate only 4-wide
  head_kernel<false><<<(NP + 255) / 256, 256, 0, stream>>>(P1, Wfl, nullptr, z, NP);
  head_kernel<true ><<<(NA + 255) / 256, 256, 0, stream>>>(A1, Wfr, bf, out, NA);
  scatter4_kernel<<<(E_PA + 255) / 256, 256, 0, stream>>>(z, src_pa, dst_pa, rinv_pa, out, E_PA);
}

// Round 2
// 877.740 us; speedup vs baseline: 2.1858x; 2.1858x over previous
//
#include <hip/hip_runtime.h>

#define NA 100000
#define NP 200000
#define NT 50000
#define DA 128
#define DP 128
#define DT 64
#define E_AP 400000
#define E_PA 400000
#define E_TP 300000
#define HD 64
#define NOUT 4
#define NEG 0.01f

// ---------------- weight prep: concat GEMM weights + folds (1 block) ----------------
__global__ void build_weights(const float* __restrict__ l1_ap_Wl, const float* __restrict__ l1_ap_Wr,
                              const float* __restrict__ l1_ap_bl,
                              const float* __restrict__ l1_pa_Wl, const float* __restrict__ l1_pa_Wr,
                              const float* __restrict__ l1_tp_Wr, const float* __restrict__ l1_tp_bl,
                              const float* __restrict__ l2_Wl, const float* __restrict__ l2_bl,
                              const float* __restrict__ l2_Wr,
                              const float* __restrict__ lin_W, const float* __restrict__ lin_b,
                              float* __restrict__ W_np, float* __restrict__ W_na,
                              float* __restrict__ blc,
                              float* __restrict__ Wfl, float* __restrict__ Wfr, float* __restrict__ bf) {
  int t = threadIdx.x;
  // W_np[k][c]: c<64 -> l1_pa_Wl[k][c] (yp); c>=64 -> l1_ap_Wr + l1_tp_Wr (P1 root)
  // W_na[k][c]: c<64 -> l1_ap_Wl[k][c] (ya); c>=64 -> l1_pa_Wr (A1 root)
  for (int i = t; i < 128 * 128; i += 256) {
    int k = i >> 7, c = i & 127;
    W_np[i] = (c < 64) ? l1_pa_Wl[k * 64 + c] : (l1_ap_Wr[k * 64 + (c - 64)] + l1_tp_Wr[k * 64 + (c - 64)]);
    W_na[i] = (c < 64) ? l1_ap_Wl[k * 64 + c] : l1_pa_Wr[k * 64 + (c - 64)];
  }
  if (t < HD) blc[t] = l1_ap_bl[t] + l1_tp_bl[t];
  // Wfl = l2_Wl @ lin_W, Wfr = l2_Wr @ lin_W  (64x4 each)
  {
    int k = t >> 2, c = t & 3;
    float s1 = 0.f, s2 = 0.f;
    for (int j = 0; j < HD; ++j) {
      float lw = lin_W[j * NOUT + c];
      s1 += l2_Wl[k * HD + j] * lw;
      s2 += l2_Wr[k * HD + j] * lw;
    }
    Wfl[t] = s1;
    Wfr[t] = s2;
  }
  if (t < NOUT) {
    float s = lin_b[t];
    for (int j = 0; j < HD; ++j) s += l2_bl[j] * lin_W[j * NOUT + t];
    bf[t] = s;
  }
}

// ---------------- degree counting + reciprocal ----------------
__global__ void count_kernel(const int* __restrict__ dst, int E, int* __restrict__ cnt) {
  int i = blockIdx.x * blockDim.x + threadIdx.x;
  if (i < E) atomicAdd(&cnt[dst[i]], 1);
}

__global__ void rinv_kernel(const int* __restrict__ cnt, float* __restrict__ rinv, int n) {
  int i = blockIdx.x * blockDim.x + threadIdx.x;
  if (i < n) rinv[i] = 1.0f / (float)max(cnt[i], 1);
}

// ---------------- register-tiled GEMM: [N x K] @ [K x COLS] ----------------
// Block tile: 128 rows x COLS cols. K-chunks of 32 staged in LDS.
// Thread tile: RT rows x 8 cols. Cols [0,64) -> out0; [64,128) -> out1 (+bias1).
#define KC 32
#define XPAD 132
template <int K, int COLS, bool HAS_BIAS1>
__global__ __launch_bounds__(256, 2) void gemm_kernel(const float* __restrict__ X,
                                                      const float* __restrict__ W,
                                                      const float* __restrict__ bias1,
                                                      float* __restrict__ out0,
                                                      float* __restrict__ out1, int N) {
  constexpr int TX = COLS / 8;        // threads along cols (16 or 8)
  constexpr int TY = 256 / TX;        // threads along rows (16 or 32)
  constexpr int RT = 128 / TY;        // rows per thread (8 or 4)
  __shared__ float Xt[KC][XPAD];      // transposed X chunk [k][row], padded
  __shared__ float Ws[KC][COLS];      // W chunk [k][col]

  const int tx = threadIdx.x % TX;
  const int ty = threadIdx.x / TX;
  const int row0 = blockIdx.x * 128;
  const int cbase = tx * 8;

  float acc[RT][8];
#pragma unroll
  for (int j = 0; j < RT; ++j)
#pragma unroll
    for (int c = 0; c < 8; ++c) acc[j][c] = 0.f;

  for (int k0 = 0; k0 < K; k0 += KC) {
    // stage X chunk (128 rows x 32 k), transposed into Xt[k][r]
#pragma unroll
    for (int i = 0; i < 4; ++i) {
      int idx = threadIdx.x + 256 * i;   // 0..1023
      int r = idx >> 3;                  // 0..127
      int kq = idx & 7;                  // 0..7 -> k-offset 4*kq
      int row = row0 + r;
      float4 v = make_float4(0.f, 0.f, 0.f, 0.f);
      if (row < N) v = *(const float4*)(X + (size_t)row * K + k0 + 4 * kq);
      Xt[4 * kq + 0][r] = v.x;
      Xt[4 * kq + 1][r] = v.y;
      Xt[4 * kq + 2][r] = v.z;
      Xt[4 * kq + 3][r] = v.w;
    }
    // stage W chunk (32 k x COLS)
#pragma unroll
    for (int i = 0; i < KC * COLS / 1024; ++i) {
      int idx = threadIdx.x + 256 * i;   // float4 index
      int kk = idx / (COLS / 4);
      int cq = idx % (COLS / 4);
      *(float4*)(&Ws[kk][4 * cq]) = *(const float4*)(W + (size_t)(k0 + kk) * COLS + 4 * cq);
    }
    __syncthreads();
#pragma unroll 2
    for (int k = 0; k < KC; ++k) {
      float a[RT], b[8];
      *(float4*)&a[0] = *(const float4*)&Xt[k][ty * RT];
      if (RT == 8) *(float4*)&a[4] = *(const float4*)&Xt[k][ty * RT + 4];
      *(float4*)&b[0] = *(const float4*)&Ws[k][cbase];
      *(float4*)&b[4] = *(const float4*)&Ws[k][cbase + 4];
#pragma unroll
      for (int j = 0; j < RT; ++j)
#pragma unroll
        for (int c = 0; c < 8; ++c) acc[j][c] += a[j] * b[c];
    }
    __syncthreads();
  }

  // epilogue
  float bv[8];
  const bool hi = (COLS == 128) && (cbase >= 64);
  if (HAS_BIAS1 && hi) {
#pragma unroll
    for (int c = 0; c < 8; ++c) bv[c] = bias1[cbase - 64 + c];
  }
#pragma unroll
  for (int j = 0; j < RT; ++j) {
    int row = row0 + ty * RT + j;
    if (row >= N) continue;
    if (!hi) {
      *(float4*)(out0 + (size_t)row * HD + cbase) = *(float4*)&acc[j][0];
      *(float4*)(out0 + (size_t)row * HD + cbase + 4) = *(float4*)&acc[j][4];
    } else {
      if (HAS_BIAS1) {
#pragma unroll
        for (int c = 0; c < 8; ++c) acc[j][c] += bv[c];
      }
      *(float4*)(out1 + (size_t)row * HD + (cbase - 64)) = *(float4*)&acc[j][0];
      *(float4*)(out1 + (size_t)row * HD + (cbase - 64) + 4) = *(float4*)&acc[j][4];
    }
  }
}

// ---------------- edge scatter: T[dst] += Y[src] * rinv[dst], 64-wide ----------------
__global__ __launch_bounds__(256) void scatter_kernel(const float* __restrict__ Y,
                                                      const int* __restrict__ src,
                                                      const int* __restrict__ dst,
                                                      const float* __restrict__ rinv,
                                                      float* __restrict__ T, int E) {
  int e = blockIdx.x * 4 + (threadIdx.x >> 6);
  int lane = threadIdx.x & 63;
  if (e >= E) return;
  int s = src[e], d = dst[e];
  float w = rinv[d];
  atomicAdd(&T[(size_t)d * HD + lane], Y[(size_t)s * HD + lane] * w);
}

// ---------------- leaky relu, vectorized ----------------
__global__ void lrelu_kernel(float4* __restrict__ T, int n4) {
  int i = blockIdx.x * blockDim.x + threadIdx.x;
  if (i < n4) {
    float4 v = T[i];
    v.x = v.x > 0.f ? v.x : NEG * v.x;
    v.y = v.y > 0.f ? v.y : NEG * v.y;
    v.z = v.z > 0.f ? v.z : NEG * v.z;
    v.w = v.w > 0.f ? v.w : NEG * v.w;
    T[i] = v;
  }
}

// ---------------- head: C[N x 4] = X[N x 64] @ W[64 x 4] (+bias) ----------------
template <bool BIAS>
__global__ __launch_bounds__(256) void head_kernel(const float* __restrict__ X,
                                                   const float* __restrict__ W,
                                                   const float* __restrict__ b,
                                                   float* __restrict__ C, int N) {
  __shared__ float Wl[HD * NOUT];
  if (threadIdx.x < HD * NOUT) Wl[threadIdx.x] = W[threadIdx.x];
  __syncthreads();
  int r = blockIdx.x * 256 + threadIdx.x;
  if (r >= N) return;
  const float4* xr = (const float4*)(X + (size_t)r * HD);
  float a0 = 0.f, a1 = 0.f, a2 = 0.f, a3 = 0.f;
#pragma unroll
  for (int k4 = 0; k4 < HD / 4; ++k4) {
    float4 x = xr[k4];
    int base = k4 * 4 * NOUT;
    a0 += x.x * Wl[base + 0] + x.y * Wl[base + 4] + x.z * Wl[base + 8] + x.w * Wl[base + 12];
    a1 += x.x * Wl[base + 1] + x.y * Wl[base + 5] + x.z * Wl[base + 9] + x.w * Wl[base + 13];
    a2 += x.x * Wl[base + 2] + x.y * Wl[base + 6] + x.z * Wl[base + 10] + x.w * Wl[base + 14];
    a3 += x.x * Wl[base + 3] + x.y * Wl[base + 7] + x.z * Wl[base + 11] + x.w * Wl[base + 15];
  }
  if (BIAS) { a0 += b[0]; a1 += b[1]; a2 += b[2]; a3 += b[3]; }
  float4 o; o.x = a0; o.y = a1; o.z = a2; o.w = a3;
  *(float4*)(C + (size_t)r * NOUT) = o;
}

// ---------------- layer-2 scatter, 4-wide ----------------
__global__ void scatter4_kernel(const float* __restrict__ z,
                                const int* __restrict__ src,
                                const int* __restrict__ dst,
                                const float* __restrict__ rinv,
                                float* __restrict__ T, int E) {
  int e = blockIdx.x * blockDim.x + threadIdx.x;
  if (e >= E) return;
  int s = src[e], d = dst[e];
  float w = rinv[d];
  float4 zv = *(const float4*)(z + (size_t)s * NOUT);
  atomicAdd(&T[(size_t)d * NOUT + 0], zv.x * w);
  atomicAdd(&T[(size_t)d * NOUT + 1], zv.y * w);
  atomicAdd(&T[(size_t)d * NOUT + 2], zv.z * w);
  atomicAdd(&T[(size_t)d * NOUT + 3], zv.w * w);
}

extern "C" void kernel_launch(void* const* d_in, const int* in_sizes, int n_in,
                              void* d_out, int out_size, void* d_ws, size_t ws_size,
                              hipStream_t stream) {
  const float* x_author = (const float*)d_in[0];
  const float* x_paper  = (const float*)d_in[1];
  const float* x_term   = (const float*)d_in[2];
  const int* src_ap = (const int*)d_in[3];
  const int* dst_ap = (const int*)d_in[4];
  const int* src_pa = (const int*)d_in[5];
  const int* dst_pa = (const int*)d_in[6];
  const int* src_tp = (const int*)d_in[7];
  const int* dst_tp = (const int*)d_in[8];
  const float* l1_ap_Wl = (const float*)d_in[11];
  const float* l1_ap_bl = (const float*)d_in[12];
  const float* l1_ap_Wr = (const float*)d_in[13];
  const float* l1_pa_Wl = (const float*)d_in[17];
  const float* l1_pa_bl = (const float*)d_in[18];
  const float* l1_pa_Wr = (const float*)d_in[19];
  const float* l2_pa_Wl = (const float*)d_in[20];
  const float* l2_pa_bl = (const float*)d_in[21];
  const float* l2_pa_Wr = (const float*)d_in[22];
  const float* l1_tp_Wl = (const float*)d_in[23];
  const float* l1_tp_bl = (const float*)d_in[24];
  const float* l1_tp_Wr = (const float*)d_in[25];
  const float* lin_W = (const float*)d_in[35];
  const float* lin_b = (const float*)d_in[36];
  float* out = (float*)d_out;

  // workspace carve-up
  float* ws = (float*)d_ws;
  float* ya = ws;  ws += (size_t)NA * HD;
  float* yp = ws;  ws += (size_t)NP * HD;
  float* yt = ws;  ws += (size_t)NT * HD;
  float* P1 = ws;  ws += (size_t)NP * HD;
  float* A1 = ws;  ws += (size_t)NA * HD;
  float* z  = ws;  ws += (size_t)NP * NOUT;
  float* rinv_ap = ws; ws += NP;
  float* rinv_tp = ws; ws += NP;
  float* rinv_pa = ws; ws += NA;
  int* cnt = (int*)ws; ws += (size_t)2 * NP + NA;
  int* cnt_ap = cnt;
  int* cnt_tp = cnt + NP;
  int* cnt_pa = cnt + 2 * NP;
  float* W_np = ws; ws += 128 * 128;  // [pa_Wl | ap_Wr+tp_Wr]
  float* W_na = ws; ws += 128 * 128;  // [ap_Wl | pa_Wr]
  float* blc = ws; ws += HD;
  float* Wfl = ws; ws += HD * NOUT;
  float* Wfr = ws; ws += HD * NOUT;
  float* bf  = ws; ws += NOUT;

  hipMemsetAsync(cnt, 0, ((size_t)2 * NP + NA) * sizeof(int), stream);
  build_weights<<<1, 256, 0, stream>>>(l1_ap_Wl, l1_ap_Wr, l1_ap_bl,
                                       l1_pa_Wl, l1_pa_Wr, l1_tp_Wr, l1_tp_bl,
                                       l2_pa_Wl, l2_pa_bl, l2_pa_Wr, lin_W, lin_b,
                                       W_np, W_na, blc, Wfl, Wfr, bf);

  count_kernel<<<(E_AP + 255) / 256, 256, 0, stream>>>(dst_ap, E_AP, cnt_ap);
  count_kernel<<<(E_TP + 255) / 256, 256, 0, stream>>>(dst_tp, E_TP, cnt_tp);
  count_kernel<<<(E_PA + 255) / 256, 256, 0, stream>>>(dst_pa, E_PA, cnt_pa);
  rinv_kernel<<<(NP + 255) / 256, 256, 0, stream>>>(cnt_ap, rinv_ap, NP);
  rinv_kernel<<<(NP + 255) / 256, 256, 0, stream>>>(cnt_tp, rinv_tp, NP);
  rinv_kernel<<<(NA + 255) / 256, 256, 0, stream>>>(cnt_pa, rinv_pa, NA);

  // fused feature transforms (register-tiled GEMMs)
  gemm_kernel<128, 128, true><<<(NP + 127) / 128, 256, 0, stream>>>(x_paper, W_np, blc, yp, P1, NP);
  gemm_kernel<128, 128, true><<<(NA + 127) / 128, 256, 0, stream>>>(x_author, W_na, l1_pa_bl, ya, A1, NA);
  gemm_kernel<64, 64, false><<<(NT + 127) / 128, 256, 0, stream>>>(x_term, l1_tp_Wl, nullptr, yt, nullptr, NT);

  // mean-aggregation fused into scatter via per-dst reciprocal counts
  scatter_kernel<<<(E_AP + 3) / 4, 256, 0, stream>>>(ya, src_ap, dst_ap, rinv_ap, P1, E_AP);
  scatter_kernel<<<(E_TP + 3) / 4, 256, 0, stream>>>(yt, src_tp, dst_tp, rinv_tp, P1, E_TP);
  scatter_kernel<<<(E_PA + 3) / 4, 256, 0, stream>>>(yp, src_pa, dst_pa, rinv_pa, A1, E_PA);

  lrelu_kernel<<<((NP * HD / 4) + 255) / 256, 256, 0, stream>>>((float4*)P1, NP * HD / 4);
  lrelu_kernel<<<((NA * HD / 4) + 255) / 256, 256, 0, stream>>>((float4*)A1, NA * HD / 4);

  // folded layer-2 + lin head: aggregate only 4-wide
  head_kernel<false><<<(NP + 255) / 256, 256, 0, stream>>>(P1, Wfl, nullptr, z, NP);
  head_kernel<true ><<<(NA + 255) / 256, 256, 0, stream>>>(A1, Wfr, bf, out, NA);
  scatter4_kernel<<<(E_PA + 255) / 256, 256, 0, stream>>>(z, src_pa, dst_pa, rinv_pa, out, E_PA);
}

// Round 3
// 749.462 us; speedup vs baseline: 2.5600x; 1.1712x over previous
//
#include <hip/hip_runtime.h>

#define NA 100000
#define NP 200000
#define NT 50000
#define E_AP 400000
#define E_PA 400000
#define E_TP 300000
#define E_TOT (E_AP + E_TP + E_PA)
#define HD 64
#define NOUT 4
#define NEG 0.01f

typedef __attribute__((ext_vector_type(8))) short bf16x8;
typedef __attribute__((ext_vector_type(4))) float f32x4;

static __device__ __forceinline__ short f2bf(float f) {
  unsigned u = __float_as_uint(f);
  unsigned r = (u + 0x7FFFu + ((u >> 16) & 1u)) >> 16;  // RNE
  return (short)r;
}

// ---------------- weight prep (parallel): bf16-transposed GEMM weights + folds ----
// Wt_np[c][k] (c in [0,128), k in [0,128)): c<64 -> l1_pa_Wl[k][c]; c>=64 -> ap_Wr+tp_Wr
// Wt_na[c][k]: c<64 -> l1_ap_Wl[k][c]; c>=64 -> l1_pa_Wr[k][c-64]
// Wt_tp[c][k] (64x64): l1_tp_Wl[k][c]
#define R_NP 16384
#define R_NA 32768
#define R_TP 36864
#define R_BLC 36928
#define R_WFL 37184
#define R_WFR 37440
#define R_BF 37444
__global__ __launch_bounds__(256) void build_kernel(
    const float* __restrict__ l1_ap_Wl, const float* __restrict__ l1_ap_bl,
    const float* __restrict__ l1_ap_Wr,
    const float* __restrict__ l1_pa_Wl, const float* __restrict__ l1_pa_bl,
    const float* __restrict__ l1_pa_Wr,
    const float* __restrict__ l1_tp_Wl, const float* __restrict__ l1_tp_bl,
    const float* __restrict__ l1_tp_Wr,
    const float* __restrict__ l2_Wl, const float* __restrict__ l2_bl,
    const float* __restrict__ l2_Wr,
    const float* __restrict__ lin_W, const float* __restrict__ lin_b,
    short* __restrict__ Wt_np, short* __restrict__ Wt_na, short* __restrict__ Wt_tp,
    float* __restrict__ blc, float* __restrict__ Wfl, float* __restrict__ Wfr,
    float* __restrict__ bf) {
  int t = blockIdx.x * 256 + threadIdx.x;
  if (t < R_NP) {
    int c = t >> 7, k = t & 127;
    float v = (c < 64) ? l1_pa_Wl[k * 64 + c]
                       : (l1_ap_Wr[k * 64 + (c - 64)] + l1_tp_Wr[k * 64 + (c - 64)]);
    Wt_np[t] = f2bf(v);
  } else if (t < R_NA) {
    int i = t - R_NP;
    int c = i >> 7, k = i & 127;
    float v = (c < 64) ? l1_ap_Wl[k * 64 + c] : l1_pa_Wr[k * 64 + (c - 64)];
    Wt_na[i] = f2bf(v);
  } else if (t < R_TP) {
    int i = t - R_NA;
    int c = i >> 6, k = i & 63;
    Wt_tp[i] = f2bf(l1_tp_Wl[k * 64 + c]);
  } else if (t < R_BLC) {
    int c = t - R_TP;
    blc[c] = l1_ap_bl[c] + l1_tp_bl[c];
  } else if (t < R_WFL) {
    int i = t - R_BLC;   // [0,256): k*4+c
    int k = i >> 2, c = i & 3;
    float s = 0.f;
    for (int j = 0; j < HD; ++j) s += l2_Wl[k * HD + j] * lin_W[j * NOUT + c];
    Wfl[i] = s;
  } else if (t < R_WFR) {
    int i = t - R_WFL;
    int k = i >> 2, c = i & 3;
    float s = 0.f;
    for (int j = 0; j < HD; ++j) s += l2_Wr[k * HD + j] * lin_W[j * NOUT + c];
    Wfr[i] = s;
  } else if (t < R_BF) {
    int c = t - R_WFR;
    float s = lin_b[c];
    for (int j = 0; j < HD; ++j) s += l2_bl[j] * lin_W[j * NOUT + c];
    bf[c] = s;
  }
}

// ---------------- merged degree counting (3 relations, one launch) ----------------
__global__ __launch_bounds__(256) void count_all(const int* __restrict__ dst_ap,
                                                 const int* __restrict__ dst_tp,
                                                 const int* __restrict__ dst_pa,
                                                 int* __restrict__ cnt_ap,
                                                 int* __restrict__ cnt_tp,
                                                 int* __restrict__ cnt_pa) {
  int i = blockIdx.x * 256 + threadIdx.x;
  if (i < E_AP) atomicAdd(&cnt_ap[dst_ap[i]], 1);
  else if (i < E_AP + E_TP) atomicAdd(&cnt_tp[dst_tp[i - E_AP]], 1);
  else if (i < E_TOT) atomicAdd(&cnt_pa[dst_pa[i - E_AP - E_TP]], 1);
}

// ---------------- MFMA bf16 GEMM: out[N x COLS] = X[N x K] @ W, split at col 64 ----
// Wave computes 16x16 tiles. A loaded direct from global fp32 (converted in-reg),
// B from bf16-transposed Wt[c][k] rows (L2-hot). No LDS, no barriers.
// m89-verified layouts: A[m=lane&15][k=quad*8+j]; B[k=quad*8+j][n=lane&15];
// D: col=lane&15, row=quad*4+reg.
template <int K, int COLS, bool HAS_OUT1>
__global__ __launch_bounds__(256) void gemm_mfma(const float* __restrict__ X,
                                                 const short* __restrict__ Wt,
                                                 const float* __restrict__ bias1,
                                                 float* __restrict__ out0,
                                                 float* __restrict__ out1, int N) {
  constexpr int NSTEP = K / 32;
  constexpr int NTILE = COLS / 16;
  const int lane = threadIdx.x & 63;
  const int w = threadIdx.x >> 6;
  const int m = lane & 15;
  const int quad = lane >> 4;
  const int rowA = blockIdx.x * 64 + w * 16 + m;
  const int rl = min(rowA, N - 1);

  bf16x8 afrag[NSTEP];
  const float* xr = X + (size_t)rl * K + quad * 8;
#pragma unroll
  for (int s = 0; s < NSTEP; ++s) {
    float4 v0 = *(const float4*)(xr + s * 32);
    float4 v1 = *(const float4*)(xr + s * 32 + 4);
    bf16x8 a;
    a[0] = f2bf(v0.x); a[1] = f2bf(v0.y); a[2] = f2bf(v0.z); a[3] = f2bf(v0.w);
    a[4] = f2bf(v1.x); a[5] = f2bf(v1.y); a[6] = f2bf(v1.z); a[7] = f2bf(v1.w);
    afrag[s] = a;
  }

  const int orow = blockIdx.x * 64 + w * 16 + quad * 4;
#pragma unroll
  for (int ct = 0; ct < NTILE; ++ct) {
    f32x4 acc = {0.f, 0.f, 0.f, 0.f};
    const short* wr = Wt + (size_t)(ct * 16 + m) * K + quad * 8;
#pragma unroll
    for (int s = 0; s < NSTEP; ++s) {
      bf16x8 b = *(const bf16x8*)(wr + s * 32);
      acc = __builtin_amdgcn_mfma_f32_16x16x32_bf16(afrag[s], b, acc, 0, 0, 0);
    }
    int col = ct * 16 + m;
    float* outp = out0;
    int ocol = col;
    float badd = 0.f;
    if constexpr (HAS_OUT1) {
      if (ct >= NTILE / 2) {
        outp = out1;
        ocol = col - 64;
        badd = bias1[ocol];
      }
    }
#pragma unroll
    for (int rg = 0; rg < 4; ++rg) {
      int r = orow + rg;
      if (r < N) outp[(size_t)r * HD + ocol] = acc[rg] + badd;
    }
  }
}

// ---------------- merged edge scatter (3 relations): T[dst] += Y[src]/deg ----------
__global__ __launch_bounds__(256) void scatter_all(
    const float* __restrict__ ya, const float* __restrict__ yt,
    const float* __restrict__ yp,
    const int* __restrict__ src_ap, const int* __restrict__ dst_ap,
    const int* __restrict__ src_tp, const int* __restrict__ dst_tp,
    const int* __restrict__ src_pa, const int* __restrict__ dst_pa,
    const int* __restrict__ cnt_ap, const int* __restrict__ cnt_tp,
    const int* __restrict__ cnt_pa,
    float* __restrict__ P1, float* __restrict__ A1) {
  int e = blockIdx.x * 4 + (threadIdx.x >> 6);
  int lane = threadIdx.x & 63;
  const float* Y;
  const int *sv, *dv, *cv;
  float* T;
  if (e < E_AP) {
    Y = ya; sv = src_ap; dv = dst_ap; cv = cnt_ap; T = P1;
  } else if (e < E_AP + E_TP) {
    e -= E_AP;
    Y = yt; sv = src_tp; dv = dst_tp; cv = cnt_tp; T = P1;
  } else if (e < E_TOT) {
    e -= E_AP + E_TP;
    Y = yp; sv = src_pa; dv = dst_pa; cv = cnt_pa; T = A1;
  } else {
    return;
  }
  int s = sv[e], d = dv[e];
  float w = 1.0f / (float)max(cv[d], 1);
  atomicAdd(&T[(size_t)d * HD + lane], Y[(size_t)s * HD + lane] * w);
}

// ---------------- head with fused LeakyReLU: C[N x 4] = lrelu(X[N x 64]) @ W (+b) ---
template <bool BIAS>
__global__ __launch_bounds__(256) void head_kernel(const float* __restrict__ X,
                                                   const float* __restrict__ W,
                                                   const float* __restrict__ b,
                                                   float* __restrict__ C, int N) {
  __shared__ float Wl[HD * NOUT];
  if (threadIdx.x < HD * NOUT) Wl[threadIdx.x] = W[threadIdx.x];
  __syncthreads();
  int r = blockIdx.x * 256 + threadIdx.x;
  if (r >= N) return;
  const float4* xr = (const float4*)(X + (size_t)r * HD);
  float a0 = 0.f, a1 = 0.f, a2 = 0.f, a3 = 0.f;
#pragma unroll
  for (int k4 = 0; k4 < HD / 4; ++k4) {
    float4 x = xr[k4];
    x.x = x.x > 0.f ? x.x : NEG * x.x;
    x.y = x.y > 0.f ? x.y : NEG * x.y;
    x.z = x.z > 0.f ? x.z : NEG * x.z;
    x.w = x.w > 0.f ? x.w : NEG * x.w;
    int base = k4 * 4 * NOUT;
    a0 += x.x * Wl[base + 0] + x.y * Wl[base + 4] + x.z * Wl[base + 8] + x.w * Wl[base + 12];
    a1 += x.x * Wl[base + 1] + x.y * Wl[base + 5] + x.z * Wl[base + 9] + x.w * Wl[base + 13];
    a2 += x.x * Wl[base + 2] + x.y * Wl[base + 6] + x.z * Wl[base + 10] + x.w * Wl[base + 14];
    a3 += x.x * Wl[base + 3] + x.y * Wl[base + 7] + x.z * Wl[base + 11] + x.w * Wl[base + 15];
  }
  if (BIAS) { a0 += b[0]; a1 += b[1]; a2 += b[2]; a3 += b[3]; }
  float4 o; o.x = a0; o.y = a1; o.z = a2; o.w = a3;
  *(float4*)(C + (size_t)r * NOUT) = o;
}

// ---------------- layer-2 scatter, 4-wide ----------------
__global__ __launch_bounds__(256) void scatter4_kernel(const float* __restrict__ z,
                                                       const int* __restrict__ src,
                                                       const int* __restrict__ dst,
                                                       const int* __restrict__ cnt,
                                                       float* __restrict__ T, int E) {
  int e = blockIdx.x * 256 + threadIdx.x;
  if (e >= E) return;
  int s = src[e], d = dst[e];
  float w = 1.0f / (float)max(cnt[d], 1);
  float4 zv = *(const float4*)(z + (size_t)s * NOUT);
  atomicAdd(&T[(size_t)d * NOUT + 0], zv.x * w);
  atomicAdd(&T[(size_t)d * NOUT + 1], zv.y * w);
  atomicAdd(&T[(size_t)d * NOUT + 2], zv.z * w);
  atomicAdd(&T[(size_t)d * NOUT + 3], zv.w * w);
}

extern "C" void kernel_launch(void* const* d_in, const int* in_sizes, int n_in,
                              void* d_out, int out_size, void* d_ws, size_t ws_size,
                              hipStream_t stream) {
  const float* x_author = (const float*)d_in[0];
  const float* x_paper  = (const float*)d_in[1];
  const float* x_term   = (const float*)d_in[2];
  const int* src_ap = (const int*)d_in[3];
  const int* dst_ap = (const int*)d_in[4];
  const int* src_pa = (const int*)d_in[5];
  const int* dst_pa = (const int*)d_in[6];
  const int* src_tp = (const int*)d_in[7];
  const int* dst_tp = (const int*)d_in[8];
  const float* l1_ap_Wl = (const float*)d_in[11];
  const float* l1_ap_bl = (const float*)d_in[12];
  const float* l1_ap_Wr = (const float*)d_in[13];
  const float* l1_pa_Wl = (const float*)d_in[17];
  const float* l1_pa_bl = (const float*)d_in[18];
  const float* l1_pa_Wr = (const float*)d_in[19];
  const float* l2_pa_Wl = (const float*)d_in[20];
  const float* l2_pa_bl = (const float*)d_in[21];
  const float* l2_pa_Wr = (const float*)d_in[22];
  const float* l1_tp_Wl = (const float*)d_in[23];
  const float* l1_tp_bl = (const float*)d_in[24];
  const float* l1_tp_Wr = (const float*)d_in[25];
  const float* lin_W = (const float*)d_in[35];
  const float* lin_b = (const float*)d_in[36];
  float* out = (float*)d_out;

  // workspace carve-up (all 16B-aligned)
  float* ws = (float*)d_ws;
  float* ya = ws;  ws += (size_t)NA * HD;
  float* yp = ws;  ws += (size_t)NP * HD;
  float* yt = ws;  ws += (size_t)NT * HD;
  float* P1 = ws;  ws += (size_t)NP * HD;
  float* A1 = ws;  ws += (size_t)NA * HD;
  float* z  = ws;  ws += (size_t)NP * NOUT;
  int* cnt = (int*)ws; ws += (size_t)2 * NP + NA;
  int* cnt_ap = cnt;
  int* cnt_tp = cnt + NP;
  int* cnt_pa = cnt + 2 * NP;
  short* Wt_np = (short*)ws; ws += 128 * 128 / 2;  // bf16 [c][k]
  short* Wt_na = (short*)ws; ws += 128 * 128 / 2;
  short* Wt_tp = (short*)ws; ws += 64 * 64 / 2;
  float* blc = ws; ws += HD;
  float* Wfl = ws; ws += HD * NOUT;
  float* Wfr = ws; ws += HD * NOUT;
  float* bf  = ws; ws += NOUT;

  hipMemsetAsync(cnt, 0, ((size_t)2 * NP + NA) * sizeof(int), stream);
  build_kernel<<<(R_BF + 255) / 256, 256, 0, stream>>>(
      l1_ap_Wl, l1_ap_bl, l1_ap_Wr, l1_pa_Wl, l1_pa_bl, l1_pa_Wr,
      l1_tp_Wl, l1_tp_bl, l1_tp_Wr, l2_pa_Wl, l2_pa_bl, l2_pa_Wr,
      lin_W, lin_b, Wt_np, Wt_na, Wt_tp, blc, Wfl, Wfr, bf);
  count_all<<<(E_TOT + 255) / 256, 256, 0, stream>>>(dst_ap, dst_tp, dst_pa,
                                                     cnt_ap, cnt_tp, cnt_pa);

  // layer-1 GEMMs via MFMA (memory-bound)
  gemm_mfma<128, 128, true><<<(NP + 63) / 64, 256, 0, stream>>>(x_paper, Wt_np, blc, yp, P1, NP);
  gemm_mfma<128, 128, true><<<(NA + 63) / 64, 256, 0, stream>>>(x_author, Wt_na, l1_pa_bl, ya, A1, NA);
  gemm_mfma<64, 64, false><<<(NT + 63) / 64, 256, 0, stream>>>(x_term, Wt_tp, nullptr, yt, nullptr, NT);

  // merged mean-aggregation scatter (3 relations)
  scatter_all<<<(E_TOT + 3) / 4, 256, 0, stream>>>(ya, yt, yp,
                                                   src_ap, dst_ap, src_tp, dst_tp,
                                                   src_pa, dst_pa,
                                                   cnt_ap, cnt_tp, cnt_pa, P1, A1);

  // folded layer-2 + lin head (LeakyReLU fused into the reads)
  head_kernel<false><<<(NP + 255) / 256, 256, 0, stream>>>(P1, Wfl, nullptr, z, NP);
  head_kernel<true ><<<(NA + 255) / 256, 256, 0, stream>>>(A1, Wfr, bf, out, NA);
  scatter4_kernel<<<(E_PA + 255) / 256, 256, 0, stream>>>(z, src_pa, dst_pa, cnt_pa, out, E_PA);
}

// Round 4
// 643.299 us; speedup vs baseline: 2.9824x; 1.1650x over previous
//
#include <hip/hip_runtime.h>

#define NA 100000
#define NP 200000
#define NT 50000
#define E_AP 400000
#define E_PA 400000
#define E_TP 300000
#define E_TOT (E_AP + E_TP + E_PA)
#define HD 64
#define NOUT 4
#define NEG 0.01f
#define M_CNT (2 * NP + NA)          /* 500000 concatenated count slots */
#define SCAN_NB ((M_CNT + 1023) / 1024)

typedef __attribute__((ext_vector_type(8))) short bf16x8;
typedef __attribute__((ext_vector_type(4))) float f32x4;

static __device__ __forceinline__ short f2bf(float f) {
  unsigned u = __float_as_uint(f);
  unsigned r = (u + 0x7FFFu + ((u >> 16) & 1u)) >> 16;  // RNE
  return (short)r;
}
static __device__ __forceinline__ float bf2f(unsigned short u) {
  return __uint_as_float((unsigned)u << 16);
}
static __device__ __forceinline__ float4 wave_reduce4(float4 v) {
#pragma unroll
  for (int m = 1; m < 64; m <<= 1) {
    v.x += __shfl_xor(v.x, m);
    v.y += __shfl_xor(v.y, m);
    v.z += __shfl_xor(v.z, m);
    v.w += __shfl_xor(v.w, m);
  }
  return v;
}

// ---------------- weight prep (parallel): bf16-transposed GEMM weights + folds ----
#define R_NP 16384
#define R_NA 32768
#define R_TP 36864
#define R_BLC 36928
#define R_WFL 37184
#define R_WFR 37440
#define R_BF 37444
__global__ __launch_bounds__(256) void build_kernel(
    const float* __restrict__ l1_ap_Wl, const float* __restrict__ l1_ap_bl,
    const float* __restrict__ l1_ap_Wr,
    const float* __restrict__ l1_pa_Wl, const float* __restrict__ l1_pa_bl,
    const float* __restrict__ l1_pa_Wr,
    const float* __restrict__ l1_tp_Wl, const float* __restrict__ l1_tp_bl,
    const float* __restrict__ l1_tp_Wr,
    const float* __restrict__ l2_Wl, const float* __restrict__ l2_bl,
    const float* __restrict__ l2_Wr,
    const float* __restrict__ lin_W, const float* __restrict__ lin_b,
    short* __restrict__ Wt_np, short* __restrict__ Wt_na, short* __restrict__ Wt_tp,
    float* __restrict__ blc, float* __restrict__ Wfl, float* __restrict__ Wfr,
    float* __restrict__ bf) {
  int t = blockIdx.x * 256 + threadIdx.x;
  if (t < R_NP) {
    int c = t >> 7, k = t & 127;
    float v = (c < 64) ? l1_pa_Wl[k * 64 + c]
                       : (l1_ap_Wr[k * 64 + (c - 64)] + l1_tp_Wr[k * 64 + (c - 64)]);
    Wt_np[t] = f2bf(v);
  } else if (t < R_NA) {
    int i = t - R_NP;
    int c = i >> 7, k = i & 127;
    float v = (c < 64) ? l1_ap_Wl[k * 64 + c] : l1_pa_Wr[k * 64 + (c - 64)];
    Wt_na[i] = f2bf(v);
  } else if (t < R_TP) {
    int i = t - R_NA;
    int c = i >> 6, k = i & 63;
    Wt_tp[i] = f2bf(l1_tp_Wl[k * 64 + c]);
  } else if (t < R_BLC) {
    int c = t - R_TP;
    blc[c] = l1_ap_bl[c] + l1_tp_bl[c];
  } else if (t < R_WFL) {
    int i = t - R_BLC;
    int k = i >> 2, c = i & 3;
    float s = 0.f;
    for (int j = 0; j < HD; ++j) s += l2_Wl[k * HD + j] * lin_W[j * NOUT + c];
    Wfl[i] = s;
  } else if (t < R_WFR) {
    int i = t - R_WFL;
    int k = i >> 2, c = i & 3;
    float s = 0.f;
    for (int j = 0; j < HD; ++j) s += l2_Wr[k * HD + j] * lin_W[j * NOUT + c];
    Wfr[i] = s;
  } else if (t < R_BF) {
    int c = t - R_WFR;
    float s = lin_b[c];
    for (int j = 0; j < HD; ++j) s += l2_bl[j] * lin_W[j * NOUT + c];
    bf[c] = s;
  }
}

// ---------------- degree counting into concatenated cnt ----------------
__global__ __launch_bounds__(256) void count_all(const int* __restrict__ dst_ap,
                                                 const int* __restrict__ dst_tp,
                                                 const int* __restrict__ dst_pa,
                                                 int* __restrict__ cnt) {
  int i = blockIdx.x * 256 + threadIdx.x;
  if (i < E_AP) atomicAdd(&cnt[dst_ap[i]], 1);
  else if (i < E_AP + E_TP) atomicAdd(&cnt[NP + dst_tp[i - E_AP]], 1);
  else if (i < E_TOT) atomicAdd(&cnt[2 * NP + dst_pa[i - E_AP - E_TP]], 1);
}

// ---------------- exclusive scan (3 kernels) ----------------
__global__ __launch_bounds__(256) void scan1(const int* __restrict__ cnt,
                                             int* __restrict__ offs,
                                             int* __restrict__ bsum) {
  __shared__ int ts[256];
  int t = threadIdx.x;
  int idx = blockIdx.x * 1024 + t * 4;
  int4 v = make_int4(0, 0, 0, 0);
  if (idx < M_CNT) v = *(const int4*)(cnt + idx);
  int s = v.x + v.y + v.z + v.w;
  ts[t] = s;
  __syncthreads();
  for (int off = 1; off < 256; off <<= 1) {
    int a = (t >= off) ? ts[t - off] : 0;
    __syncthreads();
    ts[t] += a;
    __syncthreads();
  }
  int excl = ts[t] - s;
  if (idx < M_CNT) {
    int4 o;
    o.x = excl; o.y = o.x + v.x; o.z = o.y + v.y; o.w = o.z + v.z;
    *(int4*)(offs + idx) = o;
  }
  if (t == 255) bsum[blockIdx.x] = ts[255];
}

__global__ __launch_bounds__(256) void scan2(int* __restrict__ bsum, int nb) {
  __shared__ int ts[256];
  __shared__ int carrysh;
  int t = threadIdx.x;
  int carry = 0;
  for (int base = 0; base < nb; base += 256) {
    int v = (base + t < nb) ? bsum[base + t] : 0;
    ts[t] = v;
    __syncthreads();
    for (int off = 1; off < 256; off <<= 1) {
      int a = (t >= off) ? ts[t - off] : 0;
      __syncthreads();
      ts[t] += a;
      __syncthreads();
    }
    if (base + t < nb) bsum[base + t] = carry + ts[t] - v;
    if (t == 255) carrysh = ts[255];
    __syncthreads();
    carry += carrysh;
    __syncthreads();
  }
}

__global__ __launch_bounds__(256) void scan3(int* __restrict__ offs,
                                             const int* __restrict__ bsum) {
  int add = bsum[blockIdx.x];
  int idx = blockIdx.x * 1024 + threadIdx.x * 4;
  if (idx < M_CNT) {
    int4 v = *(const int4*)(offs + idx);
    v.x += add; v.y += add; v.z += add; v.w += add;
    *(int4*)(offs + idx) = v;
  }
}

// ---------------- bucket edges by dst (offs acts as cursor; start = offs-cnt) -----
__global__ __launch_bounds__(256) void bucket_kernel(
    const int* __restrict__ src_ap, const int* __restrict__ dst_ap,
    const int* __restrict__ src_tp, const int* __restrict__ dst_tp,
    const int* __restrict__ src_pa, const int* __restrict__ dst_pa,
    int* __restrict__ offs, int* __restrict__ ebuf) {
  int i = blockIdx.x * 256 + threadIdx.x;
  int g, s;
  if (i < E_AP) { g = dst_ap[i]; s = src_ap[i]; }
  else if (i < E_AP + E_TP) { int j = i - E_AP; g = NP + dst_tp[j]; s = src_tp[j]; }
  else if (i < E_TOT) { int j = i - E_AP - E_TP; g = 2 * NP + dst_pa[j]; s = src_pa[j]; }
  else return;
  int pos = atomicAdd(&offs[g], 1);
  ebuf[pos] = s;
}

// ---------------- MFMA bf16 GEMM: y (bf16) cols [0,64) ; root (fp32,+bias) [64,128)
template <int K, int COLS, bool HAS_OUT1>
__global__ __launch_bounds__(256) void gemm_mfma(const float* __restrict__ X,
                                                 const short* __restrict__ Wt,
                                                 const float* __restrict__ bias1,
                                                 unsigned short* __restrict__ out0,
                                                 float* __restrict__ out1, int N) {
  constexpr int NSTEP = K / 32;
  constexpr int NTILE = COLS / 16;
  const int lane = threadIdx.x & 63;
  const int w = threadIdx.x >> 6;
  const int m = lane & 15;
  const int quad = lane >> 4;
  const int rowA = blockIdx.x * 64 + w * 16 + m;
  const int rl = min(rowA, N - 1);

  bf16x8 afrag[NSTEP];
  const float* xr = X + (size_t)rl * K + quad * 8;
#pragma unroll
  for (int s = 0; s < NSTEP; ++s) {
    float4 v0 = *(const float4*)(xr + s * 32);
    float4 v1 = *(const float4*)(xr + s * 32 + 4);
    bf16x8 a;
    a[0] = f2bf(v0.x); a[1] = f2bf(v0.y); a[2] = f2bf(v0.z); a[3] = f2bf(v0.w);
    a[4] = f2bf(v1.x); a[5] = f2bf(v1.y); a[6] = f2bf(v1.z); a[7] = f2bf(v1.w);
    afrag[s] = a;
  }

  const int orow = blockIdx.x * 64 + w * 16 + quad * 4;
#pragma unroll
  for (int ct = 0; ct < NTILE; ++ct) {
    f32x4 acc = {0.f, 0.f, 0.f, 0.f};
    const short* wr = Wt + (size_t)(ct * 16 + m) * K + quad * 8;
#pragma unroll
    for (int s = 0; s < NSTEP; ++s) {
      bf16x8 b = *(const bf16x8*)(wr + s * 32);
      acc = __builtin_amdgcn_mfma_f32_16x16x32_bf16(afrag[s], b, acc, 0, 0, 0);
    }
    int col = ct * 16 + m;
    if (HAS_OUT1 && ct >= NTILE / 2) {
      int ocol = col - 64;
      float badd = bias1[ocol];
#pragma unroll
      for (int rg = 0; rg < 4; ++rg) {
        int r = orow + rg;
        if (r < N) out1[(size_t)r * HD + ocol] = acc[rg] + badd;
      }
    } else {
#pragma unroll
      for (int rg = 0; rg < 4; ++rg) {
        int r = orow + rg;
        if (r < N) out0[(size_t)r * HD + col] = (unsigned short)f2bf(acc[rg]);
      }
    }
  }
}

// ---------------- paper aggregation: gather + root + lrelu + fold to z ------------
__global__ __launch_bounds__(256) void paper_agg(
    const unsigned short* __restrict__ ya, const unsigned short* __restrict__ yt,
    const float* __restrict__ P1root,
    const int* __restrict__ cnt, const int* __restrict__ offs,
    const int* __restrict__ ebuf, const float* __restrict__ Wfl,
    float* __restrict__ z) {
  int p = blockIdx.x * 4 + (threadIdx.x >> 6);
  if (p >= NP) return;
  int lane = threadIdx.x & 63;
  int endA = offs[p], cA = cnt[p];
  float accA = 0.f;
  for (int e = endA - cA; e < endA; ++e) {
    int s = ebuf[e];
    accA += bf2f(ya[(size_t)s * HD + lane]);
  }
  int endT = offs[NP + p], cT = cnt[NP + p];
  float accT = 0.f;
  for (int e = endT - cT; e < endT; ++e) {
    int s = ebuf[e];
    accT += bf2f(yt[(size_t)s * HD + lane]);
  }
  float v = P1root[(size_t)p * HD + lane] + accA / (float)max(cA, 1) + accT / (float)max(cT, 1);
  v = v > 0.f ? v : NEG * v;
  float4 wf = *(const float4*)(Wfl + lane * 4);
  float4 pz;
  pz.x = v * wf.x; pz.y = v * wf.y; pz.z = v * wf.z; pz.w = v * wf.w;
  pz = wave_reduce4(pz);
  if (lane == 0) *(float4*)(z + (size_t)p * NOUT) = pz;
}

// ---------------- author aggregation: layer-1 + layer-2 over shared pa list ------
__global__ __launch_bounds__(256) void author_agg(
    const unsigned short* __restrict__ yp, const float* __restrict__ A1root,
    const float* __restrict__ z,
    const int* __restrict__ cnt, const int* __restrict__ offs,
    const int* __restrict__ ebuf, const float* __restrict__ Wfr,
    const float* __restrict__ bf, float* __restrict__ out) {
  int a = blockIdx.x * 4 + (threadIdx.x >> 6);
  if (a >= NA) return;
  int lane = threadIdx.x & 63;
  int end = offs[2 * NP + a], c = cnt[2 * NP + a];
  float acc = 0.f;
  float4 az = make_float4(0.f, 0.f, 0.f, 0.f);
  for (int e = end - c; e < end; ++e) {
    int s = ebuf[e];
    acc += bf2f(yp[(size_t)s * HD + lane]);
    float4 zv = *(const float4*)(z + (size_t)s * NOUT);
    az.x += zv.x; az.y += zv.y; az.z += zv.z; az.w += zv.w;
  }
  float r = 1.0f / (float)max(c, 1);
  float v = A1root[(size_t)a * HD + lane] + acc * r;
  v = v > 0.f ? v : NEG * v;
  float4 wf = *(const float4*)(Wfr + lane * 4);
  float4 o;
  o.x = v * wf.x; o.y = v * wf.y; o.z = v * wf.z; o.w = v * wf.w;
  o = wave_reduce4(o);
  if (lane == 0) {
    float4 b = *(const float4*)bf;
    o.x += az.x * r + b.x;
    o.y += az.y * r + b.y;
    o.z += az.z * r + b.z;
    o.w += az.w * r + b.w;
    *(float4*)(out + (size_t)a * NOUT) = o;
  }
}

extern "C" void kernel_launch(void* const* d_in, const int* in_sizes, int n_in,
                              void* d_out, int out_size, void* d_ws, size_t ws_size,
                              hipStream_t stream) {
  const float* x_author = (const float*)d_in[0];
  const float* x_paper  = (const float*)d_in[1];
  const float* x_term   = (const float*)d_in[2];
  const int* src_ap = (const int*)d_in[3];
  const int* dst_ap = (const int*)d_in[4];
  const int* src_pa = (const int*)d_in[5];
  const int* dst_pa = (const int*)d_in[6];
  const int* src_tp = (const int*)d_in[7];
  const int* dst_tp = (const int*)d_in[8];
  const float* l1_ap_Wl = (const float*)d_in[11];
  const float* l1_ap_bl = (const float*)d_in[12];
  const float* l1_ap_Wr = (const float*)d_in[13];
  const float* l1_pa_Wl = (const float*)d_in[17];
  const float* l1_pa_bl = (const float*)d_in[18];
  const float* l1_pa_Wr = (const float*)d_in[19];
  const float* l2_pa_Wl = (const float*)d_in[20];
  const float* l2_pa_bl = (const float*)d_in[21];
  const float* l2_pa_Wr = (const float*)d_in[22];
  const float* l1_tp_Wl = (const float*)d_in[23];
  const float* l1_tp_bl = (const float*)d_in[24];
  const float* l1_tp_Wr = (const float*)d_in[25];
  const float* lin_W = (const float*)d_in[35];
  const float* lin_b = (const float*)d_in[36];
  float* out = (float*)d_out;

  // workspace carve-up (byte-based, 16B aligned blocks)
  char* wsb = (char*)d_ws;
  auto carve = [&](size_t bytes) {
    char* p = wsb;
    wsb += (bytes + 15) & ~(size_t)15;
    return p;
  };
  unsigned short* ya = (unsigned short*)carve((size_t)NA * HD * 2);
  unsigned short* yp = (unsigned short*)carve((size_t)NP * HD * 2);
  unsigned short* yt = (unsigned short*)carve((size_t)NT * HD * 2);
  float* P1root = (float*)carve((size_t)NP * HD * 4);
  float* A1root = (float*)carve((size_t)NA * HD * 4);
  float* z = (float*)carve((size_t)NP * NOUT * 4);
  int* cnt = (int*)carve((size_t)M_CNT * 4);
  int* offs = (int*)carve((size_t)M_CNT * 4);
  int* bsum = (int*)carve((size_t)SCAN_NB * 4);
  int* ebuf = (int*)carve((size_t)E_TOT * 4);
  short* Wt_np = (short*)carve(128 * 128 * 2);
  short* Wt_na = (short*)carve(128 * 128 * 2);
  short* Wt_tp = (short*)carve(64 * 64 * 2);
  float* blc = (float*)carve(HD * 4);
  float* Wfl = (float*)carve(HD * NOUT * 4);
  float* Wfr = (float*)carve(HD * NOUT * 4);
  float* bf  = (float*)carve(NOUT * 4);

  hipMemsetAsync(cnt, 0, (size_t)M_CNT * 4, stream);
  build_kernel<<<(R_BF + 255) / 256, 256, 0, stream>>>(
      l1_ap_Wl, l1_ap_bl, l1_ap_Wr, l1_pa_Wl, l1_pa_bl, l1_pa_Wr,
      l1_tp_Wl, l1_tp_bl, l1_tp_Wr, l2_pa_Wl, l2_pa_bl, l2_pa_Wr,
      lin_W, lin_b, Wt_np, Wt_na, Wt_tp, blc, Wfl, Wfr, bf);
  count_all<<<(E_TOT + 255) / 256, 256, 0, stream>>>(dst_ap, dst_tp, dst_pa, cnt);

  // exclusive scan of cnt -> offs
  scan1<<<SCAN_NB, 256, 0, stream>>>(cnt, offs, bsum);
  scan2<<<1, 256, 0, stream>>>(bsum, SCAN_NB);
  scan3<<<SCAN_NB, 256, 0, stream>>>(offs, bsum);

  // layer-1 GEMMs via MFMA; y outputs bf16, roots fp32 (+bias)
  gemm_mfma<128, 128, true><<<(NP + 63) / 64, 256, 0, stream>>>(x_paper, Wt_np, blc, yp, P1root, NP);
  gemm_mfma<128, 128, true><<<(NA + 63) / 64, 256, 0, stream>>>(x_author, Wt_na, l1_pa_bl, ya, A1root, NA);
  gemm_mfma<64, 64, false><<<(NT + 63) / 64, 256, 0, stream>>>(x_term, Wt_tp, nullptr, yt, nullptr, NT);

  // CSR bucket (offs becomes end-cursor; consumers use offs[g]-cnt[g] as start)
  bucket_kernel<<<(E_TOT + 255) / 256, 256, 0, stream>>>(src_ap, dst_ap, src_tp, dst_tp,
                                                         src_pa, dst_pa, offs, ebuf);

  // gather-based aggregation, fully atomic-free
  paper_agg<<<(NP + 3) / 4, 256, 0, stream>>>(ya, yt, P1root, cnt, offs, ebuf, Wfl, z);
  author_agg<<<(NA + 3) / 4, 256, 0, stream>>>(yp, A1root, z, cnt, offs, ebuf, Wfr, bf, out);
}

// Round 5
// 597.291 us; speedup vs baseline: 3.2122x; 1.0770x over previous
//
#include <hip/hip_runtime.h>

#define NA 100000
#define NP 200000
#define NT 50000
#define E_AP 400000
#define E_PA 400000
#define E_TP 300000
#define E_TOT (E_AP + E_TP + E_PA)
#define HD 64
#define NOUT 4
#define NEG 0.01f
#define M_CNT (2 * NP + NA)          /* 500000 concatenated count slots */
#define SCAN_NB ((M_CNT + 1023) / 1024)

typedef __attribute__((ext_vector_type(8))) short bf16x8;
typedef __attribute__((ext_vector_type(4))) float f32x4;

static __device__ __forceinline__ short f2bf(float f) {
  unsigned u = __float_as_uint(f);
  unsigned r = (u + 0x7FFFu + ((u >> 16) & 1u)) >> 16;  // RNE
  return (short)r;
}
static __device__ __forceinline__ float bf2f(unsigned short u) {
  return __uint_as_float((unsigned)u << 16);
}
static __device__ __forceinline__ float2 bf2x(unsigned int u2) {
  // unpack ushort2 (two bf16) -> two floats
  float2 r;
  r.x = __uint_as_float(u2 << 16);
  r.y = __uint_as_float(u2 & 0xFFFF0000u);
  return r;
}

// ---------------- weight prep (parallel): bf16-transposed GEMM weights + folds ----
#define R_NP 16384
#define R_NA 32768
#define R_TP 36864
#define R_BLC 36928
#define R_WFL 37184
#define R_WFR 37440
#define R_BF 37444
__global__ __launch_bounds__(256) void build_kernel(
    const float* __restrict__ l1_ap_Wl, const float* __restrict__ l1_ap_bl,
    const float* __restrict__ l1_ap_Wr,
    const float* __restrict__ l1_pa_Wl, const float* __restrict__ l1_pa_bl,
    const float* __restrict__ l1_pa_Wr,
    const float* __restrict__ l1_tp_Wl, const float* __restrict__ l1_tp_bl,
    const float* __restrict__ l1_tp_Wr,
    const float* __restrict__ l2_Wl, const float* __restrict__ l2_bl,
    const float* __restrict__ l2_Wr,
    const float* __restrict__ lin_W, const float* __restrict__ lin_b,
    short* __restrict__ Wt_np, short* __restrict__ Wt_na, short* __restrict__ Wt_tp,
    float* __restrict__ blc, float* __restrict__ Wfl, float* __restrict__ Wfr,
    float* __restrict__ bf) {
  int t = blockIdx.x * 256 + threadIdx.x;
  if (t < R_NP) {
    int c = t >> 7, k = t & 127;
    float v = (c < 64) ? l1_pa_Wl[k * 64 + c]
                       : (l1_ap_Wr[k * 64 + (c - 64)] + l1_tp_Wr[k * 64 + (c - 64)]);
    Wt_np[t] = f2bf(v);
  } else if (t < R_NA) {
    int i = t - R_NP;
    int c = i >> 7, k = i & 127;
    float v = (c < 64) ? l1_ap_Wl[k * 64 + c] : l1_pa_Wr[k * 64 + (c - 64)];
    Wt_na[i] = f2bf(v);
  } else if (t < R_TP) {
    int i = t - R_NA;
    int c = i >> 6, k = i & 63;
    Wt_tp[i] = f2bf(l1_tp_Wl[k * 64 + c]);
  } else if (t < R_BLC) {
    int c = t - R_TP;
    blc[c] = l1_ap_bl[c] + l1_tp_bl[c];
  } else if (t < R_WFL) {
    int i = t - R_BLC;
    int k = i >> 2, c = i & 3;
    float s = 0.f;
    for (int j = 0; j < HD; ++j) s += l2_Wl[k * HD + j] * lin_W[j * NOUT + c];
    Wfl[i] = s;
  } else if (t < R_WFR) {
    int i = t - R_WFL;
    int k = i >> 2, c = i & 3;
    float s = 0.f;
    for (int j = 0; j < HD; ++j) s += l2_Wr[k * HD + j] * lin_W[j * NOUT + c];
    Wfr[i] = s;
  } else if (t < R_BF) {
    int c = t - R_WFR;
    float s = lin_b[c];
    for (int j = 0; j < HD; ++j) s += l2_bl[j] * lin_W[j * NOUT + c];
    bf[c] = s;
  }
}

// ---------------- degree counting into concatenated cnt ----------------
__global__ __launch_bounds__(256) void count_all(const int* __restrict__ dst_ap,
                                                 const int* __restrict__ dst_tp,
                                                 const int* __restrict__ dst_pa,
                                                 int* __restrict__ cnt) {
  int i = blockIdx.x * 256 + threadIdx.x;
  if (i < E_AP) atomicAdd(&cnt[dst_ap[i]], 1);
  else if (i < E_AP + E_TP) atomicAdd(&cnt[NP + dst_tp[i - E_AP]], 1);
  else if (i < E_TOT) atomicAdd(&cnt[2 * NP + dst_pa[i - E_AP - E_TP]], 1);
}

// ---------------- exclusive scan (3 kernels) ----------------
__global__ __launch_bounds__(256) void scan1(const int* __restrict__ cnt,
                                             int* __restrict__ offs,
                                             int* __restrict__ bsum) {
  __shared__ int ts[256];
  int t = threadIdx.x;
  int idx = blockIdx.x * 1024 + t * 4;
  int4 v = make_int4(0, 0, 0, 0);
  if (idx < M_CNT) v = *(const int4*)(cnt + idx);
  int s = v.x + v.y + v.z + v.w;
  ts[t] = s;
  __syncthreads();
  for (int off = 1; off < 256; off <<= 1) {
    int a = (t >= off) ? ts[t - off] : 0;
    __syncthreads();
    ts[t] += a;
    __syncthreads();
  }
  int excl = ts[t] - s;
  if (idx < M_CNT) {
    int4 o;
    o.x = excl; o.y = o.x + v.x; o.z = o.y + v.y; o.w = o.z + v.z;
    *(int4*)(offs + idx) = o;
  }
  if (t == 255) bsum[blockIdx.x] = ts[255];
}

__global__ __launch_bounds__(256) void scan2(int* __restrict__ bsum, int nb) {
  __shared__ int ts[256];
  __shared__ int carrysh;
  int t = threadIdx.x;
  int carry = 0;
  for (int base = 0; base < nb; base += 256) {
    int v = (base + t < nb) ? bsum[base + t] : 0;
    ts[t] = v;
    __syncthreads();
    for (int off = 1; off < 256; off <<= 1) {
      int a = (t >= off) ? ts[t - off] : 0;
      __syncthreads();
      ts[t] += a;
      __syncthreads();
    }
    if (base + t < nb) bsum[base + t] = carry + ts[t] - v;
    if (t == 255) carrysh = ts[255];
    __syncthreads();
    carry += carrysh;
    __syncthreads();
  }
}

__global__ __launch_bounds__(256) void scan3(int* __restrict__ offs,
                                             const int* __restrict__ bsum) {
  int add = bsum[blockIdx.x];
  int idx = blockIdx.x * 1024 + threadIdx.x * 4;
  if (idx < M_CNT) {
    int4 v = *(const int4*)(offs + idx);
    v.x += add; v.y += add; v.z += add; v.w += add;
    *(int4*)(offs + idx) = v;
  }
}

// ---------------- bucket edges by dst (offs acts as cursor; start = offs-cnt) -----
__global__ __launch_bounds__(256) void bucket_kernel(
    const int* __restrict__ src_ap, const int* __restrict__ dst_ap,
    const int* __restrict__ src_tp, const int* __restrict__ dst_tp,
    const int* __restrict__ src_pa, const int* __restrict__ dst_pa,
    int* __restrict__ offs, int* __restrict__ ebuf) {
  int i = blockIdx.x * 256 + threadIdx.x;
  int g, s;
  if (i < E_AP) { g = dst_ap[i]; s = src_ap[i]; }
  else if (i < E_AP + E_TP) { int j = i - E_AP; g = NP + dst_tp[j]; s = src_tp[j]; }
  else if (i < E_TOT) { int j = i - E_AP - E_TP; g = 2 * NP + dst_pa[j]; s = src_pa[j]; }
  else return;
  int pos = atomicAdd(&offs[g], 1);
  ebuf[pos] = s;
}

// ---------------- MFMA bf16 GEMM: y (bf16) cols [0,64) ; root (bf16,+bias) [64,128)
template <int K, int COLS, bool HAS_OUT1>
__global__ __launch_bounds__(256) void gemm_mfma(const float* __restrict__ X,
                                                 const short* __restrict__ Wt,
                                                 const float* __restrict__ bias1,
                                                 unsigned short* __restrict__ out0,
                                                 unsigned short* __restrict__ out1,
                                                 int N) {
  constexpr int NSTEP = K / 32;
  constexpr int NTILE = COLS / 16;
  const int lane = threadIdx.x & 63;
  const int w = threadIdx.x >> 6;
  const int m = lane & 15;
  const int quad = lane >> 4;
  const int rowA = blockIdx.x * 64 + w * 16 + m;
  const int rl = min(rowA, N - 1);

  bf16x8 afrag[NSTEP];
  const float* xr = X + (size_t)rl * K + quad * 8;
#pragma unroll
  for (int s = 0; s < NSTEP; ++s) {
    float4 v0 = *(const float4*)(xr + s * 32);
    float4 v1 = *(const float4*)(xr + s * 32 + 4);
    bf16x8 a;
    a[0] = f2bf(v0.x); a[1] = f2bf(v0.y); a[2] = f2bf(v0.z); a[3] = f2bf(v0.w);
    a[4] = f2bf(v1.x); a[5] = f2bf(v1.y); a[6] = f2bf(v1.z); a[7] = f2bf(v1.w);
    afrag[s] = a;
  }

  const int orow = blockIdx.x * 64 + w * 16 + quad * 4;
#pragma unroll
  for (int ct = 0; ct < NTILE; ++ct) {
    f32x4 acc = {0.f, 0.f, 0.f, 0.f};
    const short* wr = Wt + (size_t)(ct * 16 + m) * K + quad * 8;
#pragma unroll
    for (int s = 0; s < NSTEP; ++s) {
      bf16x8 b = *(const bf16x8*)(wr + s * 32);
      acc = __builtin_amdgcn_mfma_f32_16x16x32_bf16(afrag[s], b, acc, 0, 0, 0);
    }
    int col = ct * 16 + m;
    if (HAS_OUT1 && ct >= NTILE / 2) {
      int ocol = col - 64;
      float badd = bias1[ocol];
#pragma unroll
      for (int rg = 0; rg < 4; ++rg) {
        int r = orow + rg;
        if (r < N) out1[(size_t)r * HD + ocol] = (unsigned short)f2bf(acc[rg] + badd);
      }
    } else {
#pragma unroll
      for (int rg = 0; rg < 4; ++rg) {
        int r = orow + rg;
        if (r < N) out0[(size_t)r * HD + col] = (unsigned short)f2bf(acc[rg]);
      }
    }
  }
}

// ---------------- paper aggregation: half-wave edge streams, fused ap+tp ---------
// lane = 32h + l; lane owns cols {2l, 2l+1}; half h processes edges h, h+2, ...
__global__ __launch_bounds__(256) void paper_agg(
    const unsigned short* __restrict__ ya, const unsigned short* __restrict__ yt,
    const unsigned short* __restrict__ P1root,
    const int* __restrict__ cnt, const int* __restrict__ offs,
    const int* __restrict__ ebuf, const float* __restrict__ Wfl,
    float* __restrict__ z) {
  int p = blockIdx.x * 4 + (threadIdx.x >> 6);
  if (p >= NP) return;
  const int lane = threadIdx.x & 63;
  const int h = lane >> 5;
  const int l = lane & 31;

  int endA = offs[p], cA = cnt[p];
  int endT = offs[NP + p], cT = cnt[NP + p];
  int startA = endA - cA, startT = endT - cT;

  float2 accA = make_float2(0.f, 0.f);
  float2 accT = make_float2(0.f, 0.f);
  int mx = max(cA, cT);
  for (int i = h; i < mx; i += 2) {
    bool vA = i < cA, vT = i < cT;
    int sA = 0, sT = 0;
    if (vA) sA = ebuf[startA + i];
    if (vT) sT = ebuf[startT + i];
    if (vA) {
      float2 u = bf2x(*(const unsigned int*)(ya + (size_t)sA * HD + 2 * l));
      accA.x += u.x; accA.y += u.y;
    }
    if (vT) {
      float2 u = bf2x(*(const unsigned int*)(yt + (size_t)sT * HD + 2 * l));
      accT.x += u.x; accT.y += u.y;
    }
  }
  // combine half-wave partial sums
  accA.x += __shfl_xor(accA.x, 32); accA.y += __shfl_xor(accA.y, 32);
  accT.x += __shfl_xor(accT.x, 32); accT.y += __shfl_xor(accT.y, 32);

  float rA = 1.0f / (float)max(cA, 1);
  float rT = 1.0f / (float)max(cT, 1);
  float2 rt = bf2x(*(const unsigned int*)(P1root + (size_t)p * HD + 2 * l));
  float vx = rt.x + accA.x * rA + accT.x * rT;
  float vy = rt.y + accA.y * rA + accT.y * rT;
  vx = vx > 0.f ? vx : NEG * vx;
  vy = vy > 0.f ? vy : NEG * vy;

  float4 w0 = *(const float4*)(Wfl + (2 * l) * 4);
  float4 w1 = *(const float4*)(Wfl + (2 * l + 1) * 4);
  float4 pz;
  pz.x = vx * w0.x + vy * w1.x;
  pz.y = vx * w0.y + vy * w1.y;
  pz.z = vx * w0.z + vy * w1.z;
  pz.w = vx * w0.w + vy * w1.w;
#pragma unroll
  for (int m = 1; m < 32; m <<= 1) {
    pz.x += __shfl_xor(pz.x, m);
    pz.y += __shfl_xor(pz.y, m);
    pz.z += __shfl_xor(pz.z, m);
    pz.w += __shfl_xor(pz.w, m);
  }
  if (lane == 0) *(float4*)(z + (size_t)p * NOUT) = pz;
}

// ---------------- author aggregation: layer-1 + layer-2 over shared pa list ------
__global__ __launch_bounds__(256) void author_agg(
    const unsigned short* __restrict__ yp, const unsigned short* __restrict__ A1root,
    const float* __restrict__ z,
    const int* __restrict__ cnt, const int* __restrict__ offs,
    const int* __restrict__ ebuf, const float* __restrict__ Wfr,
    const float* __restrict__ bf, float* __restrict__ out) {
  int a = blockIdx.x * 4 + (threadIdx.x >> 6);
  if (a >= NA) return;
  const int lane = threadIdx.x & 63;
  const int h = lane >> 5;
  const int l = lane & 31;

  int end = offs[2 * NP + a], c = cnt[2 * NP + a];
  int start = end - c;

  float2 acc = make_float2(0.f, 0.f);
  float4 az = make_float4(0.f, 0.f, 0.f, 0.f);
  for (int i = h; i < c; i += 2) {
    int s = ebuf[start + i];
    float2 u = bf2x(*(const unsigned int*)(yp + (size_t)s * HD + 2 * l));
    float4 zv = *(const float4*)(z + (size_t)s * NOUT);
    acc.x += u.x; acc.y += u.y;
    az.x += zv.x; az.y += zv.y; az.z += zv.z; az.w += zv.w;
  }
  acc.x += __shfl_xor(acc.x, 32); acc.y += __shfl_xor(acc.y, 32);
  az.x += __shfl_xor(az.x, 32);
  az.y += __shfl_xor(az.y, 32);
  az.z += __shfl_xor(az.z, 32);
  az.w += __shfl_xor(az.w, 32);

  float r = 1.0f / (float)max(c, 1);
  float2 rt = bf2x(*(const unsigned int*)(A1root + (size_t)a * HD + 2 * l));
  float vx = rt.x + acc.x * r;
  float vy = rt.y + acc.y * r;
  vx = vx > 0.f ? vx : NEG * vx;
  vy = vy > 0.f ? vy : NEG * vy;

  float4 w0 = *(const float4*)(Wfr + (2 * l) * 4);
  float4 w1 = *(const float4*)(Wfr + (2 * l + 1) * 4);
  float4 o;
  o.x = vx * w0.x + vy * w1.x;
  o.y = vx * w0.y + vy * w1.y;
  o.z = vx * w0.z + vy * w1.z;
  o.w = vx * w0.w + vy * w1.w;
#pragma unroll
  for (int m = 1; m < 32; m <<= 1) {
    o.x += __shfl_xor(o.x, m);
    o.y += __shfl_xor(o.y, m);
    o.z += __shfl_xor(o.z, m);
    o.w += __shfl_xor(o.w, m);
  }
  if (lane == 0) {
    float4 b = *(const float4*)bf;
    o.x += az.x * r + b.x;
    o.y += az.y * r + b.y;
    o.z += az.z * r + b.z;
    o.w += az.w * r + b.w;
    *(float4*)(out + (size_t)a * NOUT) = o;
  }
}

extern "C" void kernel_launch(void* const* d_in, const int* in_sizes, int n_in,
                              void* d_out, int out_size, void* d_ws, size_t ws_size,
                              hipStream_t stream) {
  const float* x_author = (const float*)d_in[0];
  const float* x_paper  = (const float*)d_in[1];
  const float* x_term   = (const float*)d_in[2];
  const int* src_ap = (const int*)d_in[3];
  const int* dst_ap = (const int*)d_in[4];
  const int* src_pa = (const int*)d_in[5];
  const int* dst_pa = (const int*)d_in[6];
  const int* src_tp = (const int*)d_in[7];
  const int* dst_tp = (const int*)d_in[8];
  const float* l1_ap_Wl = (const float*)d_in[11];
  const float* l1_ap_bl = (const float*)d_in[12];
  const float* l1_ap_Wr = (const float*)d_in[13];
  const float* l1_pa_Wl = (const float*)d_in[17];
  const float* l1_pa_bl = (const float*)d_in[18];
  const float* l1_pa_Wr = (const float*)d_in[19];
  const float* l2_pa_Wl = (const float*)d_in[20];
  const float* l2_pa_bl = (const float*)d_in[21];
  const float* l2_pa_Wr = (const float*)d_in[22];
  const float* l1_tp_Wl = (const float*)d_in[23];
  const float* l1_tp_bl = (const float*)d_in[24];
  const float* l1_tp_Wr = (const float*)d_in[25];
  const float* lin_W = (const float*)d_in[35];
  const float* lin_b = (const float*)d_in[36];
  float* out = (float*)d_out;

  // workspace carve-up (byte-based, 16B aligned blocks)
  char* wsb = (char*)d_ws;
  auto carve = [&](size_t bytes) {
    char* p = wsb;
    wsb += (bytes + 15) & ~(size_t)15;
    return p;
  };
  unsigned short* ya = (unsigned short*)carve((size_t)NA * HD * 2);
  unsigned short* yp = (unsigned short*)carve((size_t)NP * HD * 2);
  unsigned short* yt = (unsigned short*)carve((size_t)NT * HD * 2);
  unsigned short* P1root = (unsigned short*)carve((size_t)NP * HD * 2);
  unsigned short* A1root = (unsigned short*)carve((size_t)NA * HD * 2);
  float* z = (float*)carve((size_t)NP * NOUT * 4);
  int* cnt = (int*)carve((size_t)M_CNT * 4);
  int* offs = (int*)carve((size_t)M_CNT * 4);
  int* bsum = (int*)carve((size_t)SCAN_NB * 4);
  int* ebuf = (int*)carve((size_t)E_TOT * 4);
  short* Wt_np = (short*)carve(128 * 128 * 2);
  short* Wt_na = (short*)carve(128 * 128 * 2);
  short* Wt_tp = (short*)carve(64 * 64 * 2);
  float* blc = (float*)carve(HD * 4);
  float* Wfl = (float*)carve(HD * NOUT * 4);
  float* Wfr = (float*)carve(HD * NOUT * 4);
  float* bf  = (float*)carve(NOUT * 4);

  hipMemsetAsync(cnt, 0, (size_t)M_CNT * 4, stream);
  build_kernel<<<(R_BF + 255) / 256, 256, 0, stream>>>(
      l1_ap_Wl, l1_ap_bl, l1_ap_Wr, l1_pa_Wl, l1_pa_bl, l1_pa_Wr,
      l1_tp_Wl, l1_tp_bl, l1_tp_Wr, l2_pa_Wl, l2_pa_bl, l2_pa_Wr,
      lin_W, lin_b, Wt_np, Wt_na, Wt_tp, blc, Wfl, Wfr, bf);
  count_all<<<(E_TOT + 255) / 256, 256, 0, stream>>>(dst_ap, dst_tp, dst_pa, cnt);

  // exclusive scan of cnt -> offs
  scan1<<<SCAN_NB, 256, 0, stream>>>(cnt, offs, bsum);
  scan2<<<1, 256, 0, stream>>>(bsum, SCAN_NB);
  scan3<<<SCAN_NB, 256, 0, stream>>>(offs, bsum);

  // layer-1 GEMMs via MFMA; y and roots both bf16
  gemm_mfma<128, 128, true><<<(NP + 63) / 64, 256, 0, stream>>>(x_paper, Wt_np, blc, yp, P1root, NP);
  gemm_mfma<128, 128, true><<<(NA + 63) / 64, 256, 0, stream>>>(x_author, Wt_na, l1_pa_bl, ya, A1root, NA);
  gemm_mfma<64, 64, false><<<(NT + 63) / 64, 256, 0, stream>>>(x_term, Wt_tp, nullptr, yt, nullptr, NT);

  // CSR bucket (offs becomes end-cursor; consumers use offs[g]-cnt[g] as start)
  bucket_kernel<<<(E_TOT + 255) / 256, 256, 0, stream>>>(src_ap, dst_ap, src_tp, dst_tp,
                                                         src_pa, dst_pa, offs, ebuf);

  // gather-based aggregation, atomic-free, half-wave edge parallel
  paper_agg<<<(NP + 3) / 4, 256, 0, stream>>>(ya, yt, P1root, cnt, offs, ebuf, Wfl, z);
  author_agg<<<(NA + 3) / 4, 256, 0, stream>>>(yp, A1root, z, cnt, offs, ebuf, Wfr, bf, out);
}

// Round 6
// 549.097 us; speedup vs baseline: 3.4941x; 1.0878x over previous
//
#include <hip/hip_runtime.h>

#define NA 100000
#define NP 200000
#define NT 50000
#define E_AP 400000
#define E_PA 400000
#define E_TP 300000
#define E_TOT (E_AP + E_TP + E_PA)
#define HD 64
#define NOUT 4
#define NEG 0.01f
#define M_CNT (2 * NP + NA)          /* 500000 concatenated count slots */
#define SCAN_NB ((M_CNT + 1023) / 1024)

typedef __attribute__((ext_vector_type(8))) short bf16x8;
typedef __attribute__((ext_vector_type(4))) float f32x4;

static __device__ __forceinline__ short f2bf(float f) {
  unsigned u = __float_as_uint(f);
  unsigned r = (u + 0x7FFFu + ((u >> 16) & 1u)) >> 16;  // RNE
  return (short)r;
}
static __device__ __forceinline__ float bflo(unsigned u) {
  return __uint_as_float(u << 16);
}
static __device__ __forceinline__ float bfhi(unsigned u) {
  return __uint_as_float(u & 0xFFFF0000u);
}

// ---------------- weight prep (parallel): bf16-transposed GEMM weights + folds ----
#define R_NP 16384
#define R_NA 32768
#define R_TP 36864
#define R_BLC 36928
#define R_WFL 37184
#define R_WFR 37440
#define R_BF 37444
__global__ __launch_bounds__(256) void build_kernel(
    const float* __restrict__ l1_ap_Wl, const float* __restrict__ l1_ap_bl,
    const float* __restrict__ l1_ap_Wr,
    const float* __restrict__ l1_pa_Wl, const float* __restrict__ l1_pa_bl,
    const float* __restrict__ l1_pa_Wr,
    const float* __restrict__ l1_tp_Wl, const float* __restrict__ l1_tp_bl,
    const float* __restrict__ l1_tp_Wr,
    const float* __restrict__ l2_Wl, const float* __restrict__ l2_bl,
    const float* __restrict__ l2_Wr,
    const float* __restrict__ lin_W, const float* __restrict__ lin_b,
    short* __restrict__ Wt_np, short* __restrict__ Wt_na, short* __restrict__ Wt_tp,
    float* __restrict__ blc, float* __restrict__ Wfl, float* __restrict__ Wfr,
    float* __restrict__ bf) {
  int t = blockIdx.x * 256 + threadIdx.x;
  if (t < R_NP) {
    int c = t >> 7, k = t & 127;
    float v = (c < 64) ? l1_pa_Wl[k * 64 + c]
                       : (l1_ap_Wr[k * 64 + (c - 64)] + l1_tp_Wr[k * 64 + (c - 64)]);
    Wt_np[t] = f2bf(v);
  } else if (t < R_NA) {
    int i = t - R_NP;
    int c = i >> 7, k = i & 127;
    float v = (c < 64) ? l1_ap_Wl[k * 64 + c] : l1_pa_Wr[k * 64 + (c - 64)];
    Wt_na[i] = f2bf(v);
  } else if (t < R_TP) {
    int i = t - R_NA;
    int c = i >> 6, k = i & 63;
    Wt_tp[i] = f2bf(l1_tp_Wl[k * 64 + c]);
  } else if (t < R_BLC) {
    int c = t - R_TP;
    blc[c] = l1_ap_bl[c] + l1_tp_bl[c];
  } else if (t < R_WFL) {
    int i = t - R_BLC;
    int k = i >> 2, c = i & 3;
    float s = 0.f;
    for (int j = 0; j < HD; ++j) s += l2_Wl[k * HD + j] * lin_W[j * NOUT + c];
    Wfl[i] = s;
  } else if (t < R_WFR) {
    int i = t - R_WFL;
    int k = i >> 2, c = i & 3;
    float s = 0.f;
    for (int j = 0; j < HD; ++j) s += l2_Wr[k * HD + j] * lin_W[j * NOUT + c];
    Wfr[i] = s;
  } else if (t < R_BF) {
    int c = t - R_WFR;
    float s = lin_b[c];
    for (int j = 0; j < HD; ++j) s += l2_bl[j] * lin_W[j * NOUT + c];
    bf[c] = s;
  }
}

// ---------------- degree counting, int4-vectorized ----------------
__global__ __launch_bounds__(256) void count_all(const int* __restrict__ dst_ap,
                                                 const int* __restrict__ dst_tp,
                                                 const int* __restrict__ dst_pa,
                                                 int* __restrict__ cnt) {
  int i4 = (blockIdx.x * 256 + threadIdx.x) * 4;
  const int* p;
  int base;
  if (i4 < E_AP) { p = dst_ap + i4; base = 0; }
  else if (i4 < E_AP + E_TP) { p = dst_tp + (i4 - E_AP); base = NP; }
  else if (i4 < E_TOT) { p = dst_pa + (i4 - E_AP - E_TP); base = 2 * NP; }
  else return;
  int4 d = *(const int4*)p;
  atomicAdd(&cnt[base + d.x], 1);
  atomicAdd(&cnt[base + d.y], 1);
  atomicAdd(&cnt[base + d.z], 1);
  atomicAdd(&cnt[base + d.w], 1);
}

// ---------------- exclusive scan (3 kernels) ----------------
__global__ __launch_bounds__(256) void scan1(const int* __restrict__ cnt,
                                             int* __restrict__ offs,
                                             int* __restrict__ bsum) {
  __shared__ int ts[256];
  int t = threadIdx.x;
  int idx = blockIdx.x * 1024 + t * 4;
  int4 v = make_int4(0, 0, 0, 0);
  if (idx < M_CNT) v = *(const int4*)(cnt + idx);
  int s = v.x + v.y + v.z + v.w;
  ts[t] = s;
  __syncthreads();
  for (int off = 1; off < 256; off <<= 1) {
    int a = (t >= off) ? ts[t - off] : 0;
    __syncthreads();
    ts[t] += a;
    __syncthreads();
  }
  int excl = ts[t] - s;
  if (idx < M_CNT) {
    int4 o;
    o.x = excl; o.y = o.x + v.x; o.z = o.y + v.y; o.w = o.z + v.z;
    *(int4*)(offs + idx) = o;
  }
  if (t == 255) bsum[blockIdx.x] = ts[255];
}

__global__ __launch_bounds__(256) void scan2(int* __restrict__ bsum, int nb) {
  __shared__ int ts[256];
  __shared__ int carrysh;
  int t = threadIdx.x;
  int carry = 0;
  for (int base = 0; base < nb; base += 256) {
    int v = (base + t < nb) ? bsum[base + t] : 0;
    ts[t] = v;
    __syncthreads();
    for (int off = 1; off < 256; off <<= 1) {
      int a = (t >= off) ? ts[t - off] : 0;
      __syncthreads();
      ts[t] += a;
      __syncthreads();
    }
    if (base + t < nb) bsum[base + t] = carry + ts[t] - v;
    if (t == 255) carrysh = ts[255];
    __syncthreads();
    carry += carrysh;
    __syncthreads();
  }
}

__global__ __launch_bounds__(256) void scan3(int* __restrict__ offs,
                                             const int* __restrict__ bsum) {
  int add = bsum[blockIdx.x];
  int idx = blockIdx.x * 1024 + threadIdx.x * 4;
  if (idx < M_CNT) {
    int4 v = *(const int4*)(offs + idx);
    v.x += add; v.y += add; v.z += add; v.w += add;
    *(int4*)(offs + idx) = v;
  }
}

// ---------------- bucket edges by dst, int4-vectorized loads ----------------
__global__ __launch_bounds__(256) void bucket_kernel(
    const int* __restrict__ src_ap, const int* __restrict__ dst_ap,
    const int* __restrict__ src_tp, const int* __restrict__ dst_tp,
    const int* __restrict__ src_pa, const int* __restrict__ dst_pa,
    int* __restrict__ offs, int* __restrict__ ebuf) {
  int i4 = (blockIdx.x * 256 + threadIdx.x) * 4;
  const int *sp, *dp;
  int base;
  if (i4 < E_AP) { sp = src_ap + i4; dp = dst_ap + i4; base = 0; }
  else if (i4 < E_AP + E_TP) { int j = i4 - E_AP; sp = src_tp + j; dp = dst_tp + j; base = NP; }
  else if (i4 < E_TOT) { int j = i4 - E_AP - E_TP; sp = src_pa + j; dp = dst_pa + j; base = 2 * NP; }
  else return;
  int4 s = *(const int4*)sp;
  int4 d = *(const int4*)dp;
  ebuf[atomicAdd(&offs[base + d.x], 1)] = s.x;
  ebuf[atomicAdd(&offs[base + d.y], 1)] = s.y;
  ebuf[atomicAdd(&offs[base + d.z], 1)] = s.z;
  ebuf[atomicAdd(&offs[base + d.w], 1)] = s.w;
}

// ---------------- MFMA bf16 GEMM: y (bf16) cols [0,64) ; root (bf16,+bias) [64,128)
template <int K, int COLS, bool HAS_OUT1>
__global__ __launch_bounds__(256) void gemm_mfma(const float* __restrict__ X,
                                                 const short* __restrict__ Wt,
                                                 const float* __restrict__ bias1,
                                                 unsigned short* __restrict__ out0,
                                                 unsigned short* __restrict__ out1,
                                                 int N) {
  constexpr int NSTEP = K / 32;
  constexpr int NTILE = COLS / 16;
  const int lane = threadIdx.x & 63;
  const int w = threadIdx.x >> 6;
  const int m = lane & 15;
  const int quad = lane >> 4;
  const int rowA = blockIdx.x * 64 + w * 16 + m;
  const int rl = min(rowA, N - 1);

  bf16x8 afrag[NSTEP];
  const float* xr = X + (size_t)rl * K + quad * 8;
#pragma unroll
  for (int s = 0; s < NSTEP; ++s) {
    float4 v0 = *(const float4*)(xr + s * 32);
    float4 v1 = *(const float4*)(xr + s * 32 + 4);
    bf16x8 a;
    a[0] = f2bf(v0.x); a[1] = f2bf(v0.y); a[2] = f2bf(v0.z); a[3] = f2bf(v0.w);
    a[4] = f2bf(v1.x); a[5] = f2bf(v1.y); a[6] = f2bf(v1.z); a[7] = f2bf(v1.w);
    afrag[s] = a;
  }

  const int orow = blockIdx.x * 64 + w * 16 + quad * 4;
#pragma unroll
  for (int ct = 0; ct < NTILE; ++ct) {
    f32x4 acc = {0.f, 0.f, 0.f, 0.f};
    const short* wr = Wt + (size_t)(ct * 16 + m) * K + quad * 8;
#pragma unroll
    for (int s = 0; s < NSTEP; ++s) {
      bf16x8 b = *(const bf16x8*)(wr + s * 32);
      acc = __builtin_amdgcn_mfma_f32_16x16x32_bf16(afrag[s], b, acc, 0, 0, 0);
    }
    int col = ct * 16 + m;
    if (HAS_OUT1 && ct >= NTILE / 2) {
      int ocol = col - 64;
      float badd = bias1[ocol];
#pragma unroll
      for (int rg = 0; rg < 4; ++rg) {
        int r = orow + rg;
        if (r < N) out1[(size_t)r * HD + ocol] = (unsigned short)f2bf(acc[rg] + badd);
      }
    } else {
#pragma unroll
      for (int rg = 0; rg < 4; ++rg) {
        int r = orow + rg;
        if (r < N) out0[(size_t)r * HD + col] = (unsigned short)f2bf(acc[rg]);
      }
    }
  }
}

// ---------------- paper aggregation: 8 lanes/paper, 8 papers/wave ----------------
// lane = 8g + l; group g handles paper p; lane owns cols 8l..8l+7 (uint4 = 8 bf16).
__global__ __launch_bounds__(256) void paper_agg(
    const unsigned short* __restrict__ ya, const unsigned short* __restrict__ yt,
    const unsigned short* __restrict__ P1root,
    const int* __restrict__ cnt, const int* __restrict__ offs,
    const int* __restrict__ ebuf, const float* __restrict__ Wfl,
    float* __restrict__ z) {
  const int wv = threadIdx.x >> 6;
  const int lane = threadIdx.x & 63;
  const int g = lane >> 3;
  const int l = lane & 7;
  const int p = blockIdx.x * 32 + wv * 8 + g;
  const bool pv = p < NP;
  const int pc = pv ? p : NP - 1;

  const int cA = cnt[pc], cT = cnt[NP + pc];
  const int startA = offs[pc] - cA;
  const int startT = offs[NP + pc] - cT;

  float accA[8], accT[8];
#pragma unroll
  for (int j = 0; j < 8; ++j) { accA[j] = 0.f; accT[j] = 0.f; }

  const int mx = max(cA, cT);
  for (int i = 0; i < mx; ++i) {
    if (i < cA) {
      int s = ebuf[startA + i];
      uint4 u = *(const uint4*)(ya + (size_t)s * HD + 8 * l);
      accA[0] += bflo(u.x); accA[1] += bfhi(u.x);
      accA[2] += bflo(u.y); accA[3] += bfhi(u.y);
      accA[4] += bflo(u.z); accA[5] += bfhi(u.z);
      accA[6] += bflo(u.w); accA[7] += bfhi(u.w);
    }
    if (i < cT) {
      int s = ebuf[startT + i];
      uint4 u = *(const uint4*)(yt + (size_t)s * HD + 8 * l);
      accT[0] += bflo(u.x); accT[1] += bfhi(u.x);
      accT[2] += bflo(u.y); accT[3] += bfhi(u.y);
      accT[4] += bflo(u.z); accT[5] += bfhi(u.z);
      accT[6] += bflo(u.w); accT[7] += bfhi(u.w);
    }
  }

  const float rA = 1.0f / (float)max(cA, 1);
  const float rT = 1.0f / (float)max(cT, 1);
  uint4 rt = *(const uint4*)(P1root + (size_t)pc * HD + 8 * l);
  float v[8];
  v[0] = bflo(rt.x); v[1] = bfhi(rt.x); v[2] = bflo(rt.y); v[3] = bfhi(rt.y);
  v[4] = bflo(rt.z); v[5] = bfhi(rt.z); v[6] = bflo(rt.w); v[7] = bfhi(rt.w);
  float4 pz = make_float4(0.f, 0.f, 0.f, 0.f);
#pragma unroll
  for (int j = 0; j < 8; ++j) {
    float x = v[j] + accA[j] * rA + accT[j] * rT;
    x = fmaxf(x, NEG * x);  // lrelu
    float4 wf = *(const float4*)(Wfl + (8 * l + j) * 4);
    pz.x += x * wf.x; pz.y += x * wf.y; pz.z += x * wf.z; pz.w += x * wf.w;
  }
#pragma unroll
  for (int m = 1; m < 8; m <<= 1) {
    pz.x += __shfl_xor(pz.x, m);
    pz.y += __shfl_xor(pz.y, m);
    pz.z += __shfl_xor(pz.z, m);
    pz.w += __shfl_xor(pz.w, m);
  }
  if (l == 0 && pv) *(float4*)(z + (size_t)p * NOUT) = pz;
}

// ---------------- author aggregation: 8 lanes/author, layer-1+2 over pa list -----
__global__ __launch_bounds__(256) void author_agg(
    const unsigned short* __restrict__ yp, const unsigned short* __restrict__ A1root,
    const float* __restrict__ z,
    const int* __restrict__ cnt, const int* __restrict__ offs,
    const int* __restrict__ ebuf, const float* __restrict__ Wfr,
    const float* __restrict__ bf, float* __restrict__ out) {
  const int wv = threadIdx.x >> 6;
  const int lane = threadIdx.x & 63;
  const int g = lane >> 3;
  const int l = lane & 7;
  const int a = blockIdx.x * 32 + wv * 8 + g;
  const bool av = a < NA;
  const int ac = av ? a : NA - 1;

  const int c = cnt[2 * NP + ac];
  const int start = offs[2 * NP + ac] - c;

  float acc[8];
#pragma unroll
  for (int j = 0; j < 8; ++j) acc[j] = 0.f;
  float4 az = make_float4(0.f, 0.f, 0.f, 0.f);

  for (int i = 0; i < c; ++i) {
    int s = ebuf[start + i];
    uint4 u = *(const uint4*)(yp + (size_t)s * HD + 8 * l);
    float4 zv = *(const float4*)(z + (size_t)s * NOUT);  // broadcast within group
    acc[0] += bflo(u.x); acc[1] += bfhi(u.x);
    acc[2] += bflo(u.y); acc[3] += bfhi(u.y);
    acc[4] += bflo(u.z); acc[5] += bfhi(u.z);
    acc[6] += bflo(u.w); acc[7] += bfhi(u.w);
    az.x += zv.x; az.y += zv.y; az.z += zv.z; az.w += zv.w;
  }

  const float r = 1.0f / (float)max(c, 1);
  uint4 rt = *(const uint4*)(A1root + (size_t)ac * HD + 8 * l);
  float v[8];
  v[0] = bflo(rt.x); v[1] = bfhi(rt.x); v[2] = bflo(rt.y); v[3] = bfhi(rt.y);
  v[4] = bflo(rt.z); v[5] = bfhi(rt.z); v[6] = bflo(rt.w); v[7] = bfhi(rt.w);
  float4 o = make_float4(0.f, 0.f, 0.f, 0.f);
#pragma unroll
  for (int j = 0; j < 8; ++j) {
    float x = v[j] + acc[j] * r;
    x = fmaxf(x, NEG * x);
    float4 wf = *(const float4*)(Wfr + (8 * l + j) * 4);
    o.x += x * wf.x; o.y += x * wf.y; o.z += x * wf.z; o.w += x * wf.w;
  }
#pragma unroll
  for (int m = 1; m < 8; m <<= 1) {
    o.x += __shfl_xor(o.x, m);
    o.y += __shfl_xor(o.y, m);
    o.z += __shfl_xor(o.z, m);
    o.w += __shfl_xor(o.w, m);
  }
  if (l == 0 && av) {
    float4 b = *(const float4*)bf;
    o.x += az.x * r + b.x;
    o.y += az.y * r + b.y;
    o.z += az.z * r + b.z;
    o.w += az.w * r + b.w;
    *(float4*)(out + (size_t)a * NOUT) = o;
  }
}

extern "C" void kernel_launch(void* const* d_in, const int* in_sizes, int n_in,
                              void* d_out, int out_size, void* d_ws, size_t ws_size,
                              hipStream_t stream) {
  const float* x_author = (const float*)d_in[0];
  const float* x_paper  = (const float*)d_in[1];
  const float* x_term   = (const float*)d_in[2];
  const int* src_ap = (const int*)d_in[3];
  const int* dst_ap = (const int*)d_in[4];
  const int* src_pa = (const int*)d_in[5];
  const int* dst_pa = (const int*)d_in[6];
  const int* src_tp = (const int*)d_in[7];
  const int* dst_tp = (const int*)d_in[8];
  const float* l1_ap_Wl = (const float*)d_in[11];
  const float* l1_ap_bl = (const float*)d_in[12];
  const float* l1_ap_Wr = (const float*)d_in[13];
  const float* l1_pa_Wl = (const float*)d_in[17];
  const float* l1_pa_bl = (const float*)d_in[18];
  const float* l1_pa_Wr = (const float*)d_in[19];
  const float* l2_pa_Wl = (const float*)d_in[20];
  const float* l2_pa_bl = (const float*)d_in[21];
  const float* l2_pa_Wr = (const float*)d_in[22];
  const float* l1_tp_Wl = (const float*)d_in[23];
  const float* l1_tp_bl = (const float*)d_in[24];
  const float* l1_tp_Wr = (const float*)d_in[25];
  const float* lin_W = (const float*)d_in[35];
  const float* lin_b = (const float*)d_in[36];
  float* out = (float*)d_out;

  // workspace carve-up (byte-based, 16B aligned blocks)
  char* wsb = (char*)d_ws;
  auto carve = [&](size_t bytes) {
    char* p = wsb;
    wsb += (bytes + 15) & ~(size_t)15;
    return p;
  };
  unsigned short* ya = (unsigned short*)carve((size_t)NA * HD * 2);
  unsigned short* yp = (unsigned short*)carve((size_t)NP * HD * 2);
  unsigned short* yt = (unsigned short*)carve((size_t)NT * HD * 2);
  unsigned short* P1root = (unsigned short*)carve((size_t)NP * HD * 2);
  unsigned short* A1root = (unsigned short*)carve((size_t)NA * HD * 2);
  float* z = (float*)carve((size_t)NP * NOUT * 4);
  int* cnt = (int*)carve((size_t)M_CNT * 4);
  int* offs = (int*)carve((size_t)M_CNT * 4);
  int* bsum = (int*)carve((size_t)SCAN_NB * 4);
  int* ebuf = (int*)carve((size_t)E_TOT * 4);
  short* Wt_np = (short*)carve(128 * 128 * 2);
  short* Wt_na = (short*)carve(128 * 128 * 2);
  short* Wt_tp = (short*)carve(64 * 64 * 2);
  float* blc = (float*)carve(HD * 4);
  float* Wfl = (float*)carve(HD * NOUT * 4);
  float* Wfr = (float*)carve(HD * NOUT * 4);
  float* bf  = (float*)carve(NOUT * 4);

  hipMemsetAsync(cnt, 0, (size_t)M_CNT * 4, stream);
  build_kernel<<<(R_BF + 255) / 256, 256, 0, stream>>>(
      l1_ap_Wl, l1_ap_bl, l1_ap_Wr, l1_pa_Wl, l1_pa_bl, l1_pa_Wr,
      l1_tp_Wl, l1_tp_bl, l1_tp_Wr, l2_pa_Wl, l2_pa_bl, l2_pa_Wr,
      lin_W, lin_b, Wt_np, Wt_na, Wt_tp, blc, Wfl, Wfr, bf);
  count_all<<<(E_TOT / 4 + 255) / 256, 256, 0, stream>>>(dst_ap, dst_tp, dst_pa, cnt);

  // exclusive scan of cnt -> offs
  scan1<<<SCAN_NB, 256, 0, stream>>>(cnt, offs, bsum);
  scan2<<<1, 256, 0, stream>>>(bsum, SCAN_NB);
  scan3<<<SCAN_NB, 256, 0, stream>>>(offs, bsum);

  // layer-1 GEMMs via MFMA; y and roots both bf16
  gemm_mfma<128, 128, true><<<(NP + 63) / 64, 256, 0, stream>>>(x_paper, Wt_np, blc, yp, P1root, NP);
  gemm_mfma<128, 128, true><<<(NA + 63) / 64, 256, 0, stream>>>(x_author, Wt_na, l1_pa_bl, ya, A1root, NA);
  gemm_mfma<64, 64, false><<<(NT + 63) / 64, 256, 0, stream>>>(x_term, Wt_tp, nullptr, yt, nullptr, NT);

  // CSR bucket (offs becomes end-cursor; consumers use offs[g]-cnt[g] as start)
  bucket_kernel<<<(E_TOT / 4 + 255) / 256, 256, 0, stream>>>(src_ap, dst_ap, src_tp, dst_tp,
                                                             src_pa, dst_pa, offs, ebuf);

  // gather-based aggregation: 8 lanes/node, 8 nodes/wave
  paper_agg<<<(NP + 31) / 32, 256, 0, stream>>>(ya, yt, P1root, cnt, offs, ebuf, Wfl, z);
  author_agg<<<(NA + 31) / 32, 256, 0, stream>>>(yp, A1root, z, cnt, offs, ebuf, Wfr, bf, out);
}